// Round 11
// baseline (713.905 us; speedup 1.0000x reference)
//
#include <hip/hip_runtime.h>
#include <cstdint>
#include <cstddef>

#define DEVINL __device__ __forceinline__

typedef short s16x8 __attribute__((ext_vector_type(8)));   // 8 bf16 in 4 VGPRs
typedef float f32x4 __attribute__((ext_vector_type(4)));
typedef unsigned short u16x4 __attribute__((ext_vector_type(4)));
typedef unsigned short u16x8 __attribute__((ext_vector_type(8)));

DEVINL unsigned short f2bf(float f) {
  unsigned u = __float_as_uint(f);
  unsigned r = (u + 0x7FFFu + ((u >> 16) & 1u)) >> 16;
  return (unsigned short)r;
}
DEVINL float bf2f(unsigned short b) { return __uint_as_float(((unsigned)b) << 16); }

__global__ __launch_bounds__(256) void fill_i32(int* __restrict__ p, int val, int n) {
  int i = blockIdx.x * 256 + threadIdx.x;
  if (i < n) p[i] = val;
}

// ---------------- bf16 hi/lo split conversions ----------------

__global__ __launch_bounds__(256) void cvt_split(const float* __restrict__ in,
                                                 unsigned short* __restrict__ hi,
                                                 unsigned short* __restrict__ lo, int n) {
  int i = blockIdx.x * 256 + threadIdx.x;
  if (i >= n) return;
  float f = in[i];
  unsigned short h = f2bf(f);
  float r = f - bf2f(h);
  hi[i] = h;
  lo[i] = f2bf(r);
}

// all 12 weight matrices in one launch: W[K,M] fp32 -> Wt hi/lo [M,K] bf16
struct CvtWArgs {
  const float* W[12];
  int K[12];
  int M[12];
};
__global__ __launch_bounds__(256) void cvt_w_all(CvtWArgs a,
                                                 unsigned short* __restrict__ Wh,
                                                 unsigned short* __restrict__ Wl) {
  int tid = blockIdx.x * 256 + threadIdx.x;
  int mat = tid >> 16;
  int off = tid & 65535;
  if (mat >= 12) return;
  int K = a.K[mat], M = a.M[mat];
  if (off >= K * M) return;
  int k = off / M, m = off - k * M;
  float f = a.W[mat][off];
  unsigned short h = f2bf(f);
  float r = f - bf2f(h);
  size_t dst = (size_t)mat * 65536 + (size_t)m * K + k;
  Wh[dst] = h;
  Wl[dst] = f2bf(r);
}

// ---------------- LDS-tiled fused 4-matrix MFMA GEMM (bf16x3) -------
// obf: 0 = fp32 row, 1 = bf16 row (q), 2 = bf16 kv-interleaved k-slot,
//      3 = bf16 kv-interleaved v-slot.  kv row: group g holds k4 at g*8,
//      v4 at g*8+4 (one 16B lane-gather serves both in attn).
struct GemmArgs {
  const unsigned short* Wh[4];
  const unsigned short* Wl[4];
  const float* bias[4];
  float* out[4];
  int obf[4];
};

template <int KTOT>   // 192 or 256
__global__ __launch_bounds__(256, 2) void gemm4_lds(
    const unsigned short* __restrict__ Ah, const unsigned short* __restrict__ Al,
    GemmArgs args, int N, int M) {
  const int BK = 64;
  const int LDK = 72;
  __shared__ unsigned short ash[128 * LDK];
  __shared__ unsigned short asl[128 * LDK];
  __shared__ unsigned short wsh[64 * LDK];
  __shared__ unsigned short wsl[64 * LDK];
  int tid = threadIdx.x;
  int wave = tid >> 6, lane = tid & 63;
  int lrow = lane & 15, quad = lane >> 4;
  int mt = M >> 6;
  int z = blockIdx.x / mt;
  int colTile = blockIdx.x - z * mt;
  int row0 = blockIdx.y * 128;
  int col0 = colTile * 64;
  const unsigned short* __restrict__ Wh = args.Wh[z];
  const unsigned short* __restrict__ Wl = args.Wl[z];

  f32x4 acc[2][4] = {};

  for (int k0 = 0; k0 < KTOT; k0 += BK) {
    __syncthreads();
#pragma unroll
    for (int i = 0; i < 4; i++) {
      int c = tid + i * 256;
      int r = c >> 3, kq = c & 7;
      int gr = row0 + r; if (gr >= N) gr = N - 1;
      size_t g = (size_t)gr * KTOT + k0 + kq * 8;
      *(s16x8*)(ash + r * LDK + kq * 8) = *(const s16x8*)(Ah + g);
      *(s16x8*)(asl + r * LDK + kq * 8) = *(const s16x8*)(Al + g);
    }
#pragma unroll
    for (int i = 0; i < 2; i++) {
      int c = tid + i * 256;
      int r = c >> 3, kq = c & 7;
      size_t g = (size_t)(col0 + r) * KTOT + k0 + kq * 8;
      *(s16x8*)(wsh + r * LDK + kq * 8) = *(const s16x8*)(Wh + g);
      *(s16x8*)(wsl + r * LDK + kq * 8) = *(const s16x8*)(Wl + g);
    }
    __syncthreads();
#pragma unroll
    for (int kk = 0; kk < 2; kk++) {
      s16x8 fah[2], fal[2], fbh[4], fbl[4];
#pragma unroll
      for (int rf = 0; rf < 2; rf++) {
        int r = wave * 32 + rf * 16 + lrow;
        fah[rf] = *(const s16x8*)(ash + r * LDK + kk * 32 + quad * 8);
        fal[rf] = *(const s16x8*)(asl + r * LDK + kk * 32 + quad * 8);
      }
#pragma unroll
      for (int cf = 0; cf < 4; cf++) {
        int cc = cf * 16 + lrow;
        fbh[cf] = *(const s16x8*)(wsh + cc * LDK + kk * 32 + quad * 8);
        fbl[cf] = *(const s16x8*)(wsl + cc * LDK + kk * 32 + quad * 8);
      }
#pragma unroll
      for (int rf = 0; rf < 2; rf++)
#pragma unroll
        for (int cf = 0; cf < 4; cf++) {
          acc[rf][cf] = __builtin_amdgcn_mfma_f32_16x16x32_bf16(fah[rf], fbh[cf], acc[rf][cf], 0, 0, 0);
          acc[rf][cf] = __builtin_amdgcn_mfma_f32_16x16x32_bf16(fal[rf], fbh[cf], acc[rf][cf], 0, 0, 0);
          acc[rf][cf] = __builtin_amdgcn_mfma_f32_16x16x32_bf16(fah[rf], fbl[cf], acc[rf][cf], 0, 0, 0);
        }
    }
  }
  const float* __restrict__ bias = args.bias[z];
  int obf = args.obf[z];
  if (obf == 0) {
    float* __restrict__ C = args.out[z];
#pragma unroll
    for (int cf = 0; cf < 4; cf++) {
      int col = col0 + cf * 16 + lrow;
      float bv = bias[col];
#pragma unroll
      for (int rf = 0; rf < 2; rf++) {
        int rb = row0 + wave * 32 + rf * 16 + quad * 4;
#pragma unroll
        for (int r = 0; r < 4; r++) {
          int rr = rb + r;
          if (rr < N) C[(size_t)rr * M + col] = acc[rf][cf][r] + bv;
        }
      }
    }
  } else if (obf == 1) {
    unsigned short* __restrict__ C = (unsigned short*)args.out[z];
#pragma unroll
    for (int cf = 0; cf < 4; cf++) {
      int col = col0 + cf * 16 + lrow;
      float bv = bias[col];
#pragma unroll
      for (int rf = 0; rf < 2; rf++) {
        int rb = row0 + wave * 32 + rf * 16 + quad * 4;
#pragma unroll
        for (int r = 0; r < 4; r++) {
          int rr = rb + r;
          if (rr < N) C[(size_t)rr * M + col] = f2bf(acc[rf][cf][r] + bv);
        }
      }
    }
  } else {
    // kv-interleaved: elem group g = col>>2, rem = col&3
    unsigned short* __restrict__ C = (unsigned short*)args.out[z];
    int voff = (obf == 3) ? 4 : 0;
#pragma unroll
    for (int cf = 0; cf < 4; cf++) {
      int col = col0 + cf * 16 + lrow;
      float bv = bias[col];
      int coff = (col >> 2) * 8 + voff + (col & 3);
#pragma unroll
      for (int rf = 0; rf < 2; rf++) {
        int rb = row0 + wave * 32 + rf * 16 + quad * 4;
#pragma unroll
        for (int r = 0; r < 4; r++) {
          int rr = rb + r;
          if (rr < N) C[(size_t)rr * 2 * M + coff] = f2bf(acc[rf][cf][r] + bv);
        }
      }
    }
  }
}

// ---------------- counting sort of edges by dst ----------------

__global__ __launch_bounds__(256) void hist_dst(const int* __restrict__ dst,
                                                int* __restrict__ cnt, int E) {
  int e = blockIdx.x * 256 + threadIdx.x;
  if (e < E) atomicAdd(&cnt[dst[e] + 1], 1);
}

__global__ __launch_bounds__(1024) void scan_hist(const int* __restrict__ cnt,
                                                  int* __restrict__ start,
                                                  int* __restrict__ off, int N) {
  __shared__ int sums[1024];
  const int CH = 20;
  int t = threadIdx.x;
  int base = t * CH;
  int local[CH];
  int tot = 0;
  if (base < N) {
#pragma unroll
    for (int i = 0; i < CH; i++) { local[i] = cnt[base + i]; tot += local[i]; }
  }
  sums[t] = tot;
  __syncthreads();
  for (int d = 1; d < 1024; d <<= 1) {
    int v = (t >= d) ? sums[t - d] : 0;
    __syncthreads();
    sums[t] += v;
    __syncthreads();
  }
  if (base < N) {
    int run = (t == 0) ? 0 : sums[t - 1];
#pragma unroll
    for (int i = 0; i < CH; i++) { start[base + i] = run; off[base + i] = run; run += local[i]; }
    if (base + CH == N) start[N] = run;
  }
}

__global__ __launch_bounds__(256) void scatter_edges(
    const int* __restrict__ src, const int* __restrict__ dst,
    const float* __restrict__ ea, int* __restrict__ off,
    int* __restrict__ src_s, float* __restrict__ ea_s, int* __restrict__ eid_s, int E) {
  int e = blockIdx.x * 256 + threadIdx.x;
  if (e >= E) return;
  int d = dst[e] + 1;
  int pos = atomicAdd(&off[d], 1);
  src_s[pos] = src[e] + 1;
  ea_s[pos] = ea[e];
  eid_s[pos] = e;
}

// ------- fused per-dst attention: kv-interleaved single 16B gather/edge,
// no-max softmax (exact here), algebraic hoists, depth-4 pipeline.
template <int H, int LPH>
__global__ __launch_bounds__(256) void attn_fused(
    const unsigned short* __restrict__ q, const unsigned short* __restrict__ kv,
    const float* __restrict__ We,
    const int* __restrict__ start, const int* __restrict__ src_s,
    const float* __restrict__ ea_s, const int* __restrict__ eid_s,
    float* __restrict__ sc, float* __restrict__ outp,
    float* __restrict__ alpha, int Nn, float scale) {
  const int HC = H * LPH * 4;
  int w = (blockIdx.x * 256 + threadIdx.x) >> 6;
  int lane = threadIdx.x & 63;
  if (w >= Nn) return;
  int b = start[w], e = start[w + 1];
  if (b == e) return;
  bool act = lane < H * LPH;
  int idx = lane * 4;
  int head = lane / LPH;
  float4 q4 = make_float4(0.f, 0.f, 0.f, 0.f), We4 = q4;
  if (act) {
    u16x4 qv = *(const u16x4*)(q + (size_t)w * HC + idx);
    q4.x = bf2f(qv.x); q4.y = bf2f(qv.y); q4.z = bf2f(qv.z); q4.w = bf2f(qv.w);
    We4 = *(const float4*)(We + idx);
  }
  float qwe = q4.x * We4.x + q4.y * We4.y + q4.z * We4.z + q4.w * We4.w;
#pragma unroll
  for (int mm = 1; mm < LPH; mm <<= 1) qwe += __shfl_xor(qwe, mm, 64);

  float l = 0.f, tv = 0.f;
  float4 accv = make_float4(0.f, 0.f, 0.f, 0.f);

  auto step = [&](u16x8 kvv, float eav, int pos) {
    float p = q4.x * bf2f(kvv[0]) + q4.y * bf2f(kvv[1]) +
              q4.z * bf2f(kvv[2]) + q4.w * bf2f(kvv[3]);
#pragma unroll
    for (int mm = 1; mm < LPH; mm <<= 1) p += __shfl_xor(p, mm, 64);
    float es = __expf((p + eav * qwe) * scale);
    if (act && (lane % LPH) == 0) sc[(size_t)pos * H + head] = es;
    l += es;
    tv = fmaf(es, eav, tv);
    accv.x = fmaf(es, bf2f(kvv[4]), accv.x);
    accv.y = fmaf(es, bf2f(kvv[5]), accv.y);
    accv.z = fmaf(es, bf2f(kvv[6]), accv.z);
    accv.w = fmaf(es, bf2f(kvv[7]), accv.w);
  };

  u16x8 z8 = {0, 0, 0, 0, 0, 0, 0, 0};
  u16x8 kvS[4] = {z8, z8, z8, z8};
  float eaS[4] = {0.f, 0.f, 0.f, 0.f};

  auto preload = [&](int pos, int st) {
    int s = src_s[pos]; eaS[st] = ea_s[pos];
    if (act) kvS[st] = *(const u16x8*)(kv + (size_t)s * 2 * HC + lane * 8);
  };

#pragma unroll
  for (int j = 0; j < 4; j++) if (b + j < e) preload(b + j, j);

  for (int pos = b; pos < e; pos += 4) {
#pragma unroll
    for (int j = 0; j < 4; j++) {
      if (pos + j < e) {
        u16x8 kvc = kvS[j];
        float ec = eaS[j];
        if (pos + j + 4 < e) preload(pos + j + 4, j);
        step(kvc, ec, pos + j);
      }
    }
  }

  float invl = 1.0f / (l + 1e-16f);
  if (act) {
    float* orow = outp + (size_t)w * HC + idx;
    float4 o = *(float4*)orow;
    o.x += (accv.x + tv * We4.x) * invl;
    o.y += (accv.y + tv * We4.y) * invl;
    o.z += (accv.z + tv * We4.z) * invl;
    o.w += (accv.w + tv * We4.w) * invl;
    *(float4*)orow = o;
  }
  for (int pos = b; pos < e; pos++) {
    if (act && (lane % LPH) == 0) {
      alpha[(size_t)eid_s[pos] * H + head] = sc[(size_t)pos * H + head] * invl;
    }
  }
}

// ---------------- misc dense kernels ----------------

__global__ __launch_bounds__(256) void ln_relu_split(
    const float* __restrict__ in, const float* __restrict__ g,
    const float* __restrict__ b, unsigned short* __restrict__ hi,
    unsigned short* __restrict__ lo, int N) {
  int w = (blockIdx.x * 256 + threadIdx.x) >> 6;
  int lane = threadIdx.x & 63;
  if (w >= N) return;
  float4 x = *(const float4*)(in + (size_t)w * 256 + lane * 4);
  float s = x.x + x.y + x.z + x.w;
  float s2 = x.x * x.x + x.y * x.y + x.z * x.z + x.w * x.w;
  for (int m = 1; m < 64; m <<= 1) { s += __shfl_xor(s, m, 64); s2 += __shfl_xor(s2, m, 64); }
  float mu = s * (1.0f / 256.0f);
  float var = s2 * (1.0f / 256.0f) - mu * mu;
  float inv = rsqrtf(var + 1e-5f);
  float4 gv = *(const float4*)(g + lane * 4);
  float4 bv = *(const float4*)(b + lane * 4);
  float4 y;
  y.x = fmaxf(fmaf((x.x - mu) * inv, gv.x, bv.x), 0.f);
  y.y = fmaxf(fmaf((x.y - mu) * inv, gv.y, bv.y), 0.f);
  y.z = fmaxf(fmaf((x.z - mu) * inv, gv.z, bv.z), 0.f);
  y.w = fmaxf(fmaf((x.w - mu) * inv, gv.w, bv.w), 0.f);
  u16x4 yh, yl;
  yh.x = f2bf(y.x); yl.x = f2bf(y.x - bf2f(yh.x));
  yh.y = f2bf(y.y); yl.y = f2bf(y.y - bf2f(yh.y));
  yh.z = f2bf(y.z); yl.z = f2bf(y.z - bf2f(yh.z));
  yh.w = f2bf(y.w); yl.w = f2bf(y.w - bf2f(yh.w));
  *(u16x4*)(hi + (size_t)w * 256 + lane * 4) = yh;
  *(u16x4*)(lo + (size_t)w * 256 + lane * 4) = yl;
}

__global__ __launch_bounds__(192) void resid_pool2(
    const float* __restrict__ x, const float* __restrict__ x3,
    const int* __restrict__ batch, float* __restrict__ pooled,
    float* __restrict__ cnt, int N, int R) {
  int col = threadIdx.x;
  int r0 = blockIdx.x * R;
  int r1 = min(r0 + R, N);
  if (r0 >= N) return;
  float acc = 0.f;
  int cur = batch[r0];
  int run = 0;
  for (int r = r0; r < r1; r++) {
    int b = batch[r];
    if (b != cur) {
      atomicAdd(&pooled[cur * 192 + col], acc);
      if (col == 0) atomicAdd(&cnt[cur], (float)run);
      acc = 0.f; run = 0; cur = b;
    }
    size_t i = (size_t)r * 192 + col;
    acc += x[i] + fmaxf(x3[i], 0.f);
    run++;
  }
  atomicAdd(&pooled[cur * 192 + col], acc);
  if (col == 0) atomicAdd(&cnt[cur], (float)run);
}

__global__ __launch_bounds__(64) void head_mlp(
    const float* __restrict__ pooled, const float* __restrict__ cnt,
    const float* __restrict__ fc1w, const float* __restrict__ fc1b,
    const float* __restrict__ fc2w, const float* __restrict__ fc2b,
    float* __restrict__ logits) {
  int b = blockIdx.x;
  int t = threadIdx.x;
  __shared__ float p[192];
  __shared__ float hbuf[32];
  float inv = 1.0f / fmaxf(cnt[b], 1.0f);
  for (int i = t; i < 192; i += 64) p[i] = pooled[b * 192 + i] * inv;
  __syncthreads();
  if (t < 32) {
    float acc = fc1b[t];
    for (int i = 0; i < 192; i++) acc = fmaf(p[i], fc1w[i * 32 + t], acc);
    hbuf[t] = fmaxf(acc, 0.f);
  }
  __syncthreads();
  if (t < 2) {
    float acc = fc2b[t];
    for (int j = 0; j < 32; j++) acc = fmaf(hbuf[j], fc2w[j * 2 + t], acc);
    logits[b * 2 + t] = acc;
  }
}

static inline int divup(int a, int b) { return (a + b - 1) / b; }

extern "C" void kernel_launch(void* const* d_in, const int* in_sizes, int n_in,
                              void* d_out, int out_size, void* d_ws, size_t ws_size,
                              hipStream_t stream) {
  const int N = 20000, E = 320000, B = 64;
  const float* x     = (const float*)d_in[0];
  const int*   ei    = (const int*)d_in[1];
  const float* eattr = (const float*)d_in[2];
  const int*   batch = (const int*)d_in[3];
  const int* srcp = ei;
  const int* dstp = ei + E;

  const float* Wq[3]; const float* bq[3]; const float* Wk[3]; const float* bk[3];
  const float* Wv[3]; const float* bv[3]; const float* We[3]; const float* Ws[3];
  const float* bs[3];
  for (int l = 0; l < 3; l++) {
    int base = 4 + l * 9;
    Wq[l] = (const float*)d_in[base + 0]; bq[l] = (const float*)d_in[base + 1];
    Wk[l] = (const float*)d_in[base + 2]; bk[l] = (const float*)d_in[base + 3];
    Wv[l] = (const float*)d_in[base + 4]; bv[l] = (const float*)d_in[base + 5];
    We[l] = (const float*)d_in[base + 6];
    Ws[l] = (const float*)d_in[base + 7]; bs[l] = (const float*)d_in[base + 8];
  }
  const float* g1  = (const float*)d_in[31]; const float* be1 = (const float*)d_in[32];
  const float* g2  = (const float*)d_in[33]; const float* be2 = (const float*)d_in[34];
  const float* fc1w = (const float*)d_in[35]; const float* fc1b = (const float*)d_in[36];
  const float* fc2w = (const float*)d_in[37]; const float* fc2b = (const float*)d_in[38];

  float* out = (float*)d_out;
  float* logits = out;
  float* a1 = out + 128;
  float* a2 = a1 + (size_t)E * 4;
  float* a3 = a2 + (size_t)E * 4;

  float* ws = (float*)d_ws;
  size_t o = 0;
  float* qb = ws + o; o += (size_t)N * 256;   // bf16 q (N*256 u16, oversized ok)
  float* kvb = ws + o; o += (size_t)N * 256;  // bf16 kv interleaved (N*512 u16)
  float* xa = ws + o; o += (size_t)N * 256;
  float* xb = ws + o; o += (size_t)N * 256;
  float* sc = ws + o; o += (size_t)E * 6;
  int*   cntb  = (int*)(ws + o); o += N;
  int*   startb= (int*)(ws + o); o += N + 1;
  int*   offb  = (int*)(ws + o); o += N + 1;
  int*   src_s = (int*)(ws + o); o += E;
  float* ea_s  = ws + o; o += E;
  int*   eid_s = (int*)(ws + o); o += E;
  float* pooled = ws + o; o += (size_t)B * 192;
  float* cnt    = ws + o; o += B;
  unsigned short* Ah = (unsigned short*)(ws + o); o += (size_t)N * 128;
  unsigned short* Al = (unsigned short*)(ws + o); o += (size_t)N * 128;
  unsigned short* Wh12 = (unsigned short*)(ws + o); o += (size_t)12 * 32768;
  unsigned short* Wl12 = (unsigned short*)(ws + o); o += (size_t)12 * 32768;

  unsigned short* qh  = (unsigned short*)qb;
  unsigned short* kvh = (unsigned short*)kvb;

  dim3 blk(256);

  struct LayerCfg { int K, M; float scale; };
  LayerCfg cfg[3] = {
    {192, 256, 0.125f},
    {256, 256, 0.125f},
    {256, 192, 0.1767766952966369f},
  };
  CvtWArgs cwa;
  for (int l = 0; l < 3; l++) {
    cwa.W[l * 4 + 0] = Wq[l]; cwa.W[l * 4 + 1] = Wk[l];
    cwa.W[l * 4 + 2] = Wv[l]; cwa.W[l * 4 + 3] = Ws[l];
    for (int zz = 0; zz < 4; zz++) {
      cwa.K[l * 4 + zz] = cfg[l].K; cwa.M[l * 4 + zz] = cfg[l].M;
    }
  }
  cvt_w_all<<<12 * 65536 / 256, blk, 0, stream>>>(cwa, Wh12, Wl12);

  fill_i32<<<divup(N, 256), blk, 0, stream>>>(cntb, 0, N);
  hist_dst<<<divup(E, 256), blk, 0, stream>>>(dstp, cntb, E);
  scan_hist<<<1, dim3(1024), 0, stream>>>(cntb, startb, offb, N);
  scatter_edges<<<divup(E, 256), blk, 0, stream>>>(srcp, dstp, eattr, offb,
                                                  src_s, ea_s, eid_s, E);

  float*       lay_out[3] = {xa, xb, xa};
  float*       alpha_out[3] = {a1, a2, a3};

  cvt_split<<<divup(N * 192, 256), blk, 0, stream>>>(x, Ah, Al, N * 192);

  for (int l = 0; l < 3; l++) {
    int M = cfg[l].M;
    GemmArgs ga;
    float* outs[4] = {(float*)qh, (float*)kvh, (float*)kvh, lay_out[l]};
    const float* biases[4] = {bq[l], bk[l], bv[l], bs[l]};
    int obfs[4] = {1, 2, 3, 0};
    for (int z = 0; z < 4; z++) {
      ga.Wh[z] = Wh12 + (size_t)(l * 4 + z) * 65536;
      ga.Wl[z] = Wl12 + (size_t)(l * 4 + z) * 65536;
      ga.bias[z] = biases[z];
      ga.out[z] = outs[z];
      ga.obf[z] = obfs[z];
    }
    dim3 gg((M >> 6) * 4, divup(N, 128));
    if (l == 0)      gemm4_lds<192><<<gg, blk, 0, stream>>>(Ah, Al, ga, N, M);
    else             gemm4_lds<256><<<gg, blk, 0, stream>>>(Ah, Al, ga, N, M);

    dim3 gat(divup(N * 64, 256));
    if (l < 2) {
      attn_fused<4, 16><<<gat, blk, 0, stream>>>(qh, kvh, We[l], startb, src_s,
                                                 ea_s, eid_s, sc, lay_out[l],
                                                 alpha_out[l], N, cfg[l].scale);
    } else {
      attn_fused<6, 8><<<gat, blk, 0, stream>>>(qh, kvh, We[l], startb, src_s,
                                                ea_s, eid_s, sc, lay_out[l],
                                                alpha_out[l], N, cfg[l].scale);
    }
    if (l == 0) ln_relu_split<<<divup(N, 4), blk, 0, stream>>>(xa, g1, be1, Ah, Al, N);
    if (l == 1) ln_relu_split<<<divup(N, 4), blk, 0, stream>>>(xb, g2, be2, Ah, Al, N);
  }

  fill_i32<<<divup(B * 192 + B, 256), blk, 0, stream>>>((int*)pooled, 0, B * 192 + B);
  resid_pool2<<<divup(N, 128), dim3(192), 0, stream>>>(x, xa, batch, pooled, cnt, N, 128);
  head_mlp<<<B, dim3(64), 0, stream>>>(pooled, cnt, fc1w, fc1b, fc2w, fc2b, logits);
}

// Round 13
// 641.934 us; speedup vs baseline: 1.1121x; 1.1121x over previous
//
#include <hip/hip_runtime.h>
#include <cstdint>
#include <cstddef>

#define DEVINL __device__ __forceinline__

typedef short s16x8 __attribute__((ext_vector_type(8)));   // 8 bf16 in 4 VGPRs
typedef float f32x4 __attribute__((ext_vector_type(4)));
typedef unsigned short u16x4 __attribute__((ext_vector_type(4)));
typedef unsigned short u16x8 __attribute__((ext_vector_type(8)));

DEVINL unsigned short f2bf(float f) {
  unsigned u = __float_as_uint(f);
  unsigned r = (u + 0x7FFFu + ((u >> 16) & 1u)) >> 16;
  return (unsigned short)r;
}
DEVINL float bf2f(unsigned short b) { return __uint_as_float(((unsigned)b) << 16); }

__global__ __launch_bounds__(256) void fill_i32(int* __restrict__ p, int val, int n) {
  int i = blockIdx.x * 256 + threadIdx.x;
  if (i < n) p[i] = val;
}

// ---------------- bf16 hi/lo split conversions ----------------

__global__ __launch_bounds__(256) void cvt_split(const float* __restrict__ in,
                                                 unsigned short* __restrict__ hi,
                                                 unsigned short* __restrict__ lo, int n) {
  int i = blockIdx.x * 256 + threadIdx.x;
  if (i >= n) return;
  float f = in[i];
  unsigned short h = f2bf(f);
  float r = f - bf2f(h);
  hi[i] = h;
  lo[i] = f2bf(r);
}

// all 12 weight matrices in one launch: W[K,M] fp32 -> Wt hi/lo [M,K] bf16
struct CvtWArgs {
  const float* W[12];
  int K[12];
  int M[12];
};
__global__ __launch_bounds__(256) void cvt_w_all(CvtWArgs a,
                                                 unsigned short* __restrict__ Wh,
                                                 unsigned short* __restrict__ Wl) {
  int tid = blockIdx.x * 256 + threadIdx.x;
  int mat = tid >> 16;
  int off = tid & 65535;
  if (mat >= 12) return;
  int K = a.K[mat], M = a.M[mat];
  if (off >= K * M) return;
  int k = off / M, m = off - k * M;
  float f = a.W[mat][off];
  unsigned short h = f2bf(f);
  float r = f - bf2f(h);
  size_t dst = (size_t)mat * 65536 + (size_t)m * K + k;
  Wh[dst] = h;
  Wl[dst] = f2bf(r);
}

// ---------------- LDS-tiled fused 4-matrix MFMA GEMM -------
// XOR-swizzled unpadded LDS (rows = 64 u16 = 128 B; 16B-chunk kq stored at
// slot kq^(r&7)) — conflict-free like +8 padding but 48 KB -> 3 blocks/CU.
// bf16-out z (q/kv) use bf16x2 (skip a_hi*b_lo: below their own bf16 store
// rounding); fp32 skip path keeps bf16x3.  [R11: logits passed -> verified]
// obf: 0 = fp32 row, 1 = bf16 row (q), 2/3 = bf16 kv-interleaved k/v slot.
struct GemmArgs {
  const unsigned short* Wh[4];
  const unsigned short* Wl[4];
  const float* bias[4];
  float* out[4];
  int obf[4];
};

template <int KTOT>   // 192 or 256
__global__ __launch_bounds__(256, 3) void gemm4_lds(
    const unsigned short* __restrict__ Ah, const unsigned short* __restrict__ Al,
    GemmArgs args, int N, int M) {
  const int BK = 64;
  __shared__ unsigned short ash[128 * 64];
  __shared__ unsigned short asl[128 * 64];
  __shared__ unsigned short wsh[64 * 64];
  __shared__ unsigned short wsl[64 * 64];
  int tid = threadIdx.x;
  int wave = tid >> 6, lane = tid & 63;
  int lrow = lane & 15, quad = lane >> 4;
  int mt = M >> 6;
  int z = blockIdx.x / mt;
  int colTile = blockIdx.x - z * mt;
  int row0 = blockIdx.y * 128;
  int col0 = colTile * 64;
  const unsigned short* __restrict__ Wh = args.Wh[z];
  const unsigned short* __restrict__ Wl = args.Wl[z];
  const bool full = (args.obf[z] == 0);

  f32x4 acc[2][4] = {};

  for (int k0 = 0; k0 < KTOT; k0 += BK) {
    __syncthreads();
#pragma unroll
    for (int i = 0; i < 4; i++) {
      int c = tid + i * 256;
      int r = c >> 3, kq = c & 7;
      int sq = kq ^ (r & 7);
      int gr = row0 + r; if (gr >= N) gr = N - 1;
      size_t g = (size_t)gr * KTOT + k0 + kq * 8;
      *(s16x8*)(ash + r * 64 + sq * 8) = *(const s16x8*)(Ah + g);
      *(s16x8*)(asl + r * 64 + sq * 8) = *(const s16x8*)(Al + g);
    }
#pragma unroll
    for (int i = 0; i < 2; i++) {
      int c = tid + i * 256;
      int r = c >> 3, kq = c & 7;
      int sq = kq ^ (r & 7);
      size_t g = (size_t)(col0 + r) * KTOT + k0 + kq * 8;
      *(s16x8*)(wsh + r * 64 + sq * 8) = *(const s16x8*)(Wh + g);
      if (full)
        *(s16x8*)(wsl + r * 64 + sq * 8) = *(const s16x8*)(Wl + g);
    }
    __syncthreads();
#pragma unroll
    for (int kk = 0; kk < 2; kk++) {
      s16x8 fah[2], fal[2], fbh[4], fbl[4];
#pragma unroll
      for (int rf = 0; rf < 2; rf++) {
        int r = wave * 32 + rf * 16 + lrow;
        int sq = (kk * 4 + quad) ^ (lrow & 7);
        fah[rf] = *(const s16x8*)(ash + r * 64 + sq * 8);
        fal[rf] = *(const s16x8*)(asl + r * 64 + sq * 8);
      }
#pragma unroll
      for (int cf = 0; cf < 4; cf++) {
        int cc = cf * 16 + lrow;
        int sq = (kk * 4 + quad) ^ (lrow & 7);
        fbh[cf] = *(const s16x8*)(wsh + cc * 64 + sq * 8);
        if (full) fbl[cf] = *(const s16x8*)(wsl + cc * 64 + sq * 8);
      }
#pragma unroll
      for (int rf = 0; rf < 2; rf++)
#pragma unroll
        for (int cf = 0; cf < 4; cf++) {
          acc[rf][cf] = __builtin_amdgcn_mfma_f32_16x16x32_bf16(fah[rf], fbh[cf], acc[rf][cf], 0, 0, 0);
          acc[rf][cf] = __builtin_amdgcn_mfma_f32_16x16x32_bf16(fal[rf], fbh[cf], acc[rf][cf], 0, 0, 0);
          if (full)
            acc[rf][cf] = __builtin_amdgcn_mfma_f32_16x16x32_bf16(fah[rf], fbl[cf], acc[rf][cf], 0, 0, 0);
        }
    }
  }
  const float* __restrict__ bias = args.bias[z];
  int obf = args.obf[z];
  if (obf == 0) {
    float* __restrict__ C = args.out[z];
#pragma unroll
    for (int cf = 0; cf < 4; cf++) {
      int col = col0 + cf * 16 + lrow;
      float bv = bias[col];
#pragma unroll
      for (int rf = 0; rf < 2; rf++) {
        int rb = row0 + wave * 32 + rf * 16 + quad * 4;
#pragma unroll
        for (int r = 0; r < 4; r++) {
          int rr = rb + r;
          if (rr < N) C[(size_t)rr * M + col] = acc[rf][cf][r] + bv;
        }
      }
    }
  } else if (obf == 1) {
    unsigned short* __restrict__ C = (unsigned short*)args.out[z];
#pragma unroll
    for (int cf = 0; cf < 4; cf++) {
      int col = col0 + cf * 16 + lrow;
      float bv = bias[col];
#pragma unroll
      for (int rf = 0; rf < 2; rf++) {
        int rb = row0 + wave * 32 + rf * 16 + quad * 4;
#pragma unroll
        for (int r = 0; r < 4; r++) {
          int rr = rb + r;
          if (rr < N) C[(size_t)rr * M + col] = f2bf(acc[rf][cf][r] + bv);
        }
      }
    }
  } else {
    unsigned short* __restrict__ C = (unsigned short*)args.out[z];
    int voff = (obf == 3) ? 4 : 0;
#pragma unroll
    for (int cf = 0; cf < 4; cf++) {
      int col = col0 + cf * 16 + lrow;
      float bv = bias[col];
      int coff = (col >> 2) * 8 + voff + (col & 3);
#pragma unroll
      for (int rf = 0; rf < 2; rf++) {
        int rb = row0 + wave * 32 + rf * 16 + quad * 4;
#pragma unroll
        for (int r = 0; r < 4; r++) {
          int rr = rb + r;
          if (rr < N) C[(size_t)rr * 2 * M + coff] = f2bf(acc[rf][cf][r] + bv);
        }
      }
    }
  }
}

// ---------------- counting sort of edges by dst ----------------

__global__ __launch_bounds__(256) void hist_dst(const int* __restrict__ dst,
                                                int* __restrict__ cnt, int E) {
  int e = blockIdx.x * 256 + threadIdx.x;
  if (e < E) atomicAdd(&cnt[dst[e] + 1], 1);
}

__global__ __launch_bounds__(1024) void scan_hist(const int* __restrict__ cnt,
                                                  int* __restrict__ start,
                                                  int* __restrict__ off, int N) {
  __shared__ int sums[1024];
  const int CH = 20;
  int t = threadIdx.x;
  int base = t * CH;
  int local[CH];
  int tot = 0;
  if (base < N) {
#pragma unroll
    for (int i = 0; i < CH; i++) { local[i] = cnt[base + i]; tot += local[i]; }
  }
  sums[t] = tot;
  __syncthreads();
  for (int d = 1; d < 1024; d <<= 1) {
    int v = (t >= d) ? sums[t - d] : 0;
    __syncthreads();
    sums[t] += v;
    __syncthreads();
  }
  if (base < N) {
    int run = (t == 0) ? 0 : sums[t - 1];
#pragma unroll
    for (int i = 0; i < CH; i++) { start[base + i] = run; off[base + i] = run; run += local[i]; }
    if (base + CH == N) start[N] = run;
  }
}

__global__ __launch_bounds__(256) void scatter_edges(
    const int* __restrict__ src, const int* __restrict__ dst,
    const float* __restrict__ ea, int* __restrict__ off,
    int* __restrict__ src_s, float* __restrict__ ea_s, int* __restrict__ eid_s, int E) {
  int e = blockIdx.x * 256 + threadIdx.x;
  if (e >= E) return;
  int d = dst[e] + 1;
  int pos = atomicAdd(&off[d], 1);
  src_s[pos] = src[e] + 1;
  ea_s[pos] = ea[e];
  eid_s[pos] = e;
}

// ------- fused per-dst attention: kv-interleaved single 16B gather/edge,
// no-max softmax (exact here), algebraic hoists, depth-4 pipeline,
// lane-parallel alpha writeback.
// R11 BUG FIX: invl lives per head-group (shfl_xor reduces within LPH lanes
// only); writeback lanes must pull the invl of head h_of via __shfl from
// lane h_of*LPH — NOT use their own lane's invl.
template <int H, int LPH>
__global__ __launch_bounds__(256) void attn_fused(
    const unsigned short* __restrict__ q, const unsigned short* __restrict__ kv,
    const float* __restrict__ We,
    const int* __restrict__ start, const int* __restrict__ src_s,
    const float* __restrict__ ea_s, const int* __restrict__ eid_s,
    float* __restrict__ sc, float* __restrict__ outp,
    float* __restrict__ alpha, int Nn, float scale) {
  const int HC = H * LPH * 4;
  int w = (blockIdx.x * 256 + threadIdx.x) >> 6;
  int lane = threadIdx.x & 63;
  if (w >= Nn) return;
  int b = start[w], e = start[w + 1];
  if (b == e) return;
  bool act = lane < H * LPH;
  int idx = lane * 4;
  int head = lane / LPH;
  float4 q4 = make_float4(0.f, 0.f, 0.f, 0.f), We4 = q4;
  if (act) {
    u16x4 qv = *(const u16x4*)(q + (size_t)w * HC + idx);
    q4.x = bf2f(qv.x); q4.y = bf2f(qv.y); q4.z = bf2f(qv.z); q4.w = bf2f(qv.w);
    We4 = *(const float4*)(We + idx);
  }
  float qwe = q4.x * We4.x + q4.y * We4.y + q4.z * We4.z + q4.w * We4.w;
#pragma unroll
  for (int mm = 1; mm < LPH; mm <<= 1) qwe += __shfl_xor(qwe, mm, 64);

  float l = 0.f, tv = 0.f;
  float4 accv = make_float4(0.f, 0.f, 0.f, 0.f);

  auto step = [&](u16x8 kvv, float eav, int pos) {
    float p = q4.x * bf2f(kvv[0]) + q4.y * bf2f(kvv[1]) +
              q4.z * bf2f(kvv[2]) + q4.w * bf2f(kvv[3]);
#pragma unroll
    for (int mm = 1; mm < LPH; mm <<= 1) p += __shfl_xor(p, mm, 64);
    float es = __expf((p + eav * qwe) * scale);
    if (act && (lane % LPH) == 0) sc[(size_t)pos * H + head] = es;
    l += es;
    tv = fmaf(es, eav, tv);
    accv.x = fmaf(es, bf2f(kvv[4]), accv.x);
    accv.y = fmaf(es, bf2f(kvv[5]), accv.y);
    accv.z = fmaf(es, bf2f(kvv[6]), accv.z);
    accv.w = fmaf(es, bf2f(kvv[7]), accv.w);
  };

  u16x8 z8 = {0, 0, 0, 0, 0, 0, 0, 0};
  u16x8 kvS[4] = {z8, z8, z8, z8};
  float eaS[4] = {0.f, 0.f, 0.f, 0.f};

  auto preload = [&](int pos, int st) {
    int s = src_s[pos]; eaS[st] = ea_s[pos];
    if (act) kvS[st] = *(const u16x8*)(kv + (size_t)s * 2 * HC + lane * 8);
  };

#pragma unroll
  for (int j = 0; j < 4; j++) if (b + j < e) preload(b + j, j);

  for (int pos = b; pos < e; pos += 4) {
#pragma unroll
    for (int j = 0; j < 4; j++) {
      if (pos + j < e) {
        u16x8 kvc = kvS[j];
        float ec = eaS[j];
        if (pos + j + 4 < e) preload(pos + j + 4, j);
        step(kvc, ec, pos + j);
      }
    }
  }

  float invl = 1.0f / (l + 1e-16f);
  if (act) {
    float* orow = outp + (size_t)w * HC + idx;
    float4 o = *(float4*)orow;
    o.x += (accv.x + tv * We4.x) * invl;
    o.y += (accv.y + tv * We4.y) * invl;
    o.z += (accv.z + tv * We4.z) * invl;
    o.w += (accv.w + tv * We4.w) * invl;
    *(float4*)orow = o;
  }
  // lane-parallel alpha writeback: 64/H positions per iteration.
  {
    int len = e - b;
    const int PCH = 64 / H;
    int p_of = lane / H;
    int h_of = lane - p_of * H;
    float myinv = __shfl(invl, h_of * LPH, 64);   // head h_of's denominator
    __threadfence_block();                        // sc stores -> cross-lane reads
    for (int base = 0; base < len; base += PCH) {
      int po = base + p_of;
      if (p_of < PCH && po < len) {
        int pos = b + po;
        float es = sc[(size_t)pos * H + h_of];
        alpha[(size_t)eid_s[pos] * H + h_of] = es * myinv;
      }
    }
  }
}

// ---------------- misc dense kernels ----------------

__global__ __launch_bounds__(256) void ln_relu_split(
    const float* __restrict__ in, const float* __restrict__ g,
    const float* __restrict__ b, unsigned short* __restrict__ hi,
    unsigned short* __restrict__ lo, int N) {
  int w = (blockIdx.x * 256 + threadIdx.x) >> 6;
  int lane = threadIdx.x & 63;
  if (w >= N) return;
  float4 x = *(const float4*)(in + (size_t)w * 256 + lane * 4);
  float s = x.x + x.y + x.z + x.w;
  float s2 = x.x * x.x + x.y * x.y + x.z * x.z + x.w * x.w;
  for (int m = 1; m < 64; m <<= 1) { s += __shfl_xor(s, m, 64); s2 += __shfl_xor(s2, m, 64); }
  float mu = s * (1.0f / 256.0f);
  float var = s2 * (1.0f / 256.0f) - mu * mu;
  float inv = rsqrtf(var + 1e-5f);
  float4 gv = *(const float4*)(g + lane * 4);
  float4 bv = *(const float4*)(b + lane * 4);
  float4 y;
  y.x = fmaxf(fmaf((x.x - mu) * inv, gv.x, bv.x), 0.f);
  y.y = fmaxf(fmaf((x.y - mu) * inv, gv.y, bv.y), 0.f);
  y.z = fmaxf(fmaf((x.z - mu) * inv, gv.z, bv.z), 0.f);
  y.w = fmaxf(fmaf((x.w - mu) * inv, gv.w, bv.w), 0.f);
  u16x4 yh, yl;
  yh.x = f2bf(y.x); yl.x = f2bf(y.x - bf2f(yh.x));
  yh.y = f2bf(y.y); yl.y = f2bf(y.y - bf2f(yh.y));
  yh.z = f2bf(y.z); yl.z = f2bf(y.z - bf2f(yh.z));
  yh.w = f2bf(y.w); yl.w = f2bf(y.w - bf2f(yh.w));
  *(u16x4*)(hi + (size_t)w * 256 + lane * 4) = yh;
  *(u16x4*)(lo + (size_t)w * 256 + lane * 4) = yl;
}

__global__ __launch_bounds__(192) void resid_pool2(
    const float* __restrict__ x, const float* __restrict__ x3,
    const int* __restrict__ batch, float* __restrict__ pooled,
    float* __restrict__ cnt, int N, int R) {
  int col = threadIdx.x;
  int r0 = blockIdx.x * R;
  int r1 = min(r0 + R, N);
  if (r0 >= N) return;
  float acc = 0.f;
  int cur = batch[r0];
  int run = 0;
  for (int r = r0; r < r1; r++) {
    int b = batch[r];
    if (b != cur) {
      atomicAdd(&pooled[cur * 192 + col], acc);
      if (col == 0) atomicAdd(&cnt[cur], (float)run);
      acc = 0.f; run = 0; cur = b;
    }
    size_t i = (size_t)r * 192 + col;
    acc += x[i] + fmaxf(x3[i], 0.f);
    run++;
  }
  atomicAdd(&pooled[cur * 192 + col], acc);
  if (col == 0) atomicAdd(&cnt[cur], (float)run);
}

__global__ __launch_bounds__(64) void head_mlp(
    const float* __restrict__ pooled, const float* __restrict__ cnt,
    const float* __restrict__ fc1w, const float* __restrict__ fc1b,
    const float* __restrict__ fc2w, const float* __restrict__ fc2b,
    float* __restrict__ logits) {
  int b = blockIdx.x;
  int t = threadIdx.x;
  __shared__ float p[192];
  __shared__ float hbuf[32];
  float inv = 1.0f / fmaxf(cnt[b], 1.0f);
  for (int i = t; i < 192; i += 64) p[i] = pooled[b * 192 + i] * inv;
  __syncthreads();
  if (t < 32) {
    float acc = fc1b[t];
    for (int i = 0; i < 192; i++) acc = fmaf(p[i], fc1w[i * 32 + t], acc);
    hbuf[t] = fmaxf(acc, 0.f);
  }
  __syncthreads();
  if (t < 2) {
    float acc = fc2b[t];
    for (int j = 0; j < 32; j++) acc = fmaf(hbuf[j], fc2w[j * 2 + t], acc);
    logits[b * 2 + t] = acc;
  }
}

static inline int divup(int a, int b) { return (a + b - 1) / b; }

extern "C" void kernel_launch(void* const* d_in, const int* in_sizes, int n_in,
                              void* d_out, int out_size, void* d_ws, size_t ws_size,
                              hipStream_t stream) {
  const int N = 20000, E = 320000, B = 64;
  const float* x     = (const float*)d_in[0];
  const int*   ei    = (const int*)d_in[1];
  const float* eattr = (const float*)d_in[2];
  const int*   batch = (const int*)d_in[3];
  const int* srcp = ei;
  const int* dstp = ei + E;

  const float* Wq[3]; const float* bq[3]; const float* Wk[3]; const float* bk[3];
  const float* Wv[3]; const float* bv[3]; const float* We[3]; const float* Ws[3];
  const float* bs[3];
  for (int l = 0; l < 3; l++) {
    int base = 4 + l * 9;
    Wq[l] = (const float*)d_in[base + 0]; bq[l] = (const float*)d_in[base + 1];
    Wk[l] = (const float*)d_in[base + 2]; bk[l] = (const float*)d_in[base + 3];
    Wv[l] = (const float*)d_in[base + 4]; bv[l] = (const float*)d_in[base + 5];
    We[l] = (const float*)d_in[base + 6];
    Ws[l] = (const float*)d_in[base + 7]; bs[l] = (const float*)d_in[base + 8];
  }
  const float* g1  = (const float*)d_in[31]; const float* be1 = (const float*)d_in[32];
  const float* g2  = (const float*)d_in[33]; const float* be2 = (const float*)d_in[34];
  const float* fc1w = (const float*)d_in[35]; const float* fc1b = (const float*)d_in[36];
  const float* fc2w = (const float*)d_in[37]; const float* fc2b = (const float*)d_in[38];

  float* out = (float*)d_out;
  float* logits = out;
  float* a1 = out + 128;
  float* a2 = a1 + (size_t)E * 4;
  float* a3 = a2 + (size_t)E * 4;

  float* ws = (float*)d_ws;
  size_t o = 0;
  float* qb = ws + o; o += (size_t)N * 256;   // bf16 q (oversized ok)
  float* kvb = ws + o; o += (size_t)N * 256;  // bf16 kv interleaved (N*512 u16)
  float* xa = ws + o; o += (size_t)N * 256;
  float* xb = ws + o; o += (size_t)N * 256;
  float* sc = ws + o; o += (size_t)E * 6;
  int*   cntb  = (int*)(ws + o); o += N;
  int*   startb= (int*)(ws + o); o += N + 1;
  int*   offb  = (int*)(ws + o); o += N + 1;
  int*   src_s = (int*)(ws + o); o += E;
  float* ea_s  = ws + o; o += E;
  int*   eid_s = (int*)(ws + o); o += E;
  float* pooled = ws + o; o += (size_t)B * 192;
  float* cnt    = ws + o; o += B;
  unsigned short* Ah = (unsigned short*)(ws + o); o += (size_t)N * 128;
  unsigned short* Al = (unsigned short*)(ws + o); o += (size_t)N * 128;
  unsigned short* Wh12 = (unsigned short*)(ws + o); o += (size_t)12 * 32768;
  unsigned short* Wl12 = (unsigned short*)(ws + o); o += (size_t)12 * 32768;

  unsigned short* qh  = (unsigned short*)qb;
  unsigned short* kvh = (unsigned short*)kvb;

  dim3 blk(256);

  struct LayerCfg { int K, M; float scale; };
  LayerCfg cfg[3] = {
    {192, 256, 0.125f},
    {256, 256, 0.125f},
    {256, 192, 0.1767766952966369f},
  };
  CvtWArgs cwa;
  for (int l = 0; l < 3; l++) {
    cwa.W[l * 4 + 0] = Wq[l]; cwa.W[l * 4 + 1] = Wk[l];
    cwa.W[l * 4 + 2] = Wv[l]; cwa.W[l * 4 + 3] = Ws[l];
    for (int zz = 0; zz < 4; zz++) {
      cwa.K[l * 4 + zz] = cfg[l].K; cwa.M[l * 4 + zz] = cfg[l].M;
    }
  }
  cvt_w_all<<<12 * 65536 / 256, blk, 0, stream>>>(cwa, Wh12, Wl12);

  fill_i32<<<divup(N, 256), blk, 0, stream>>>(cntb, 0, N);
  hist_dst<<<divup(E, 256), blk, 0, stream>>>(dstp, cntb, E);
  scan_hist<<<1, dim3(1024), 0, stream>>>(cntb, startb, offb, N);
  scatter_edges<<<divup(E, 256), blk, 0, stream>>>(srcp, dstp, eattr, offb,
                                                  src_s, ea_s, eid_s, E);

  float*       lay_out[3] = {xa, xb, xa};
  float*       alpha_out[3] = {a1, a2, a3};

  cvt_split<<<divup(N * 192, 256), blk, 0, stream>>>(x, Ah, Al, N * 192);

  for (int l = 0; l < 3; l++) {
    int M = cfg[l].M;
    GemmArgs ga;
    float* outs[4] = {(float*)qh, (float*)kvh, (float*)kvh, lay_out[l]};
    const float* biases[4] = {bq[l], bk[l], bv[l], bs[l]};
    int obfs[4] = {1, 2, 3, 0};
    for (int z = 0; z < 4; z++) {
      ga.Wh[z] = Wh12 + (size_t)(l * 4 + z) * 65536;
      ga.Wl[z] = Wl12 + (size_t)(l * 4 + z) * 65536;
      ga.bias[z] = biases[z];
      ga.out[z] = outs[z];
      ga.obf[z] = obfs[z];
    }
    dim3 gg((M >> 6) * 4, divup(N, 128));
    if (l == 0)      gemm4_lds<192><<<gg, blk, 0, stream>>>(Ah, Al, ga, N, M);
    else             gemm4_lds<256><<<gg, blk, 0, stream>>>(Ah, Al, ga, N, M);

    dim3 gat(divup(N * 64, 256));
    if (l < 2) {
      attn_fused<4, 16><<<gat, blk, 0, stream>>>(qh, kvh, We[l], startb, src_s,
                                                 ea_s, eid_s, sc, lay_out[l],
                                                 alpha_out[l], N, cfg[l].scale);
    } else {
      attn_fused<6, 8><<<gat, blk, 0, stream>>>(qh, kvh, We[l], startb, src_s,
                                                ea_s, eid_s, sc, lay_out[l],
                                                alpha_out[l], N, cfg[l].scale);
    }
    if (l == 0) ln_relu_split<<<divup(N, 4), blk, 0, stream>>>(xa, g1, be1, Ah, Al, N);
    if (l == 1) ln_relu_split<<<divup(N, 4), blk, 0, stream>>>(xb, g2, be2, Ah, Al, N);
  }

  fill_i32<<<divup(B * 192 + B, 256), blk, 0, stream>>>((int*)pooled, 0, B * 192 + B);
  resid_pool2<<<divup(N, 128), dim3(192), 0, stream>>>(x, xa, batch, pooled, cnt, N, 128);
  head_mlp<<<B, dim3(64), 0, stream>>>(pooled, cnt, fc1w, fc1b, fc2w, fc2b, logits);
}

// Round 14
// 637.111 us; speedup vs baseline: 1.1205x; 1.0076x over previous
//
#include <hip/hip_runtime.h>
#include <cstdint>
#include <cstddef>

#define DEVINL __device__ __forceinline__

typedef short s16x8 __attribute__((ext_vector_type(8)));   // 8 bf16 in 4 VGPRs
typedef float f32x4 __attribute__((ext_vector_type(4)));
typedef unsigned short u16x4 __attribute__((ext_vector_type(4)));
typedef unsigned short u16x8 __attribute__((ext_vector_type(8)));

DEVINL unsigned short f2bf(float f) {
  unsigned u = __float_as_uint(f);
  unsigned r = (u + 0x7FFFu + ((u >> 16) & 1u)) >> 16;
  return (unsigned short)r;
}
DEVINL float bf2f(unsigned short b) { return __uint_as_float(((unsigned)b) << 16); }

__global__ __launch_bounds__(256) void fill_i32(int* __restrict__ p, int val, int n) {
  int i = blockIdx.x * 256 + threadIdx.x;
  if (i < n) p[i] = val;
}

// ---------------- bf16 hi/lo split conversions ----------------

__global__ __launch_bounds__(256) void cvt_split(const float* __restrict__ in,
                                                 unsigned short* __restrict__ hi,
                                                 unsigned short* __restrict__ lo, int n) {
  int i = blockIdx.x * 256 + threadIdx.x;
  if (i >= n) return;
  float f = in[i];
  unsigned short h = f2bf(f);
  float r = f - bf2f(h);
  hi[i] = h;
  lo[i] = f2bf(r);
}

// all 12 weight matrices in one launch: W[K,M] fp32 -> Wt hi/lo [M,K] bf16
struct CvtWArgs {
  const float* W[12];
  int K[12];
  int M[12];
};
__global__ __launch_bounds__(256) void cvt_w_all(CvtWArgs a,
                                                 unsigned short* __restrict__ Wh,
                                                 unsigned short* __restrict__ Wl) {
  int tid = blockIdx.x * 256 + threadIdx.x;
  int mat = tid >> 16;
  int off = tid & 65535;
  if (mat >= 12) return;
  int K = a.K[mat], M = a.M[mat];
  if (off >= K * M) return;
  int k = off / M, m = off - k * M;
  float f = a.W[mat][off];
  unsigned short h = f2bf(f);
  float r = f - bf2f(h);
  size_t dst = (size_t)mat * 65536 + (size_t)m * K + k;
  Wh[dst] = h;
  Wl[dst] = f2bf(r);
}

// ---------------- LDS-tiled fused 4-matrix MFMA GEMM -------
// XOR-swizzled unpadded LDS, 48 KB -> 3 blocks/CU.  bf16x2 for bf16-consumed
// outputs, bf16x3 for the fp32 skip path.  R13: register-prefetch double
// buffer — step k+1's global loads issue right after step k's LDS stores, so
// their latency overlaps compute instead of sitting exposed between barriers
// (R12 counters: MfmaUtil 13%, VALU 12%, 75% idle = exposed staging latency).
// obf: 0 = fp32 row, 1 = bf16 row (q), 2/3 = bf16 kv-interleaved k/v slot.
struct GemmArgs {
  const unsigned short* Wh[4];
  const unsigned short* Wl[4];
  const float* bias[4];
  float* out[4];
  int obf[4];
};

template <int KTOT>   // 192 or 256
__global__ __launch_bounds__(256, 3) void gemm4_lds(
    const unsigned short* __restrict__ Ah, const unsigned short* __restrict__ Al,
    GemmArgs args, int N, int M) {
  const int BK = 64;
  __shared__ unsigned short ash[128 * 64];
  __shared__ unsigned short asl[128 * 64];
  __shared__ unsigned short wsh[64 * 64];
  __shared__ unsigned short wsl[64 * 64];
  int tid = threadIdx.x;
  int wave = tid >> 6, lane = tid & 63;
  int lrow = lane & 15, quad = lane >> 4;
  int mt = M >> 6;
  int z = blockIdx.x / mt;
  int colTile = blockIdx.x - z * mt;
  int row0 = blockIdx.y * 128;
  int col0 = colTile * 64;
  const unsigned short* __restrict__ Wh = args.Wh[z];
  const unsigned short* __restrict__ Wl = args.Wl[z];
  const bool full = (args.obf[z] == 0);

  // per-thread staging geometry (loop-invariant)
  int ar[4], asq[4];
  size_t agoff[4];
#pragma unroll
  for (int i = 0; i < 4; i++) {
    int c = tid + i * 256;
    ar[i] = c >> 3;
    int kq = c & 7;
    asq[i] = kq ^ (ar[i] & 7);
    int gr = row0 + ar[i]; if (gr >= N) gr = N - 1;
    agoff[i] = (size_t)gr * KTOT + kq * 8;
  }
  int wr[2], wsq[2];
  size_t wgoff[2];
#pragma unroll
  for (int i = 0; i < 2; i++) {
    int c = tid + i * 256;
    wr[i] = c >> 3;
    int kq = c & 7;
    wsq[i] = kq ^ (wr[i] & 7);
    wgoff[i] = (size_t)(col0 + wr[i]) * KTOT + kq * 8;
  }

  // prologue: prefetch step 0
  s16x8 pa_h[4], pa_l[4], pw_h[2], pw_l[2];
#pragma unroll
  for (int i = 0; i < 4; i++) {
    pa_h[i] = *(const s16x8*)(Ah + agoff[i]);
    pa_l[i] = *(const s16x8*)(Al + agoff[i]);
  }
#pragma unroll
  for (int i = 0; i < 2; i++) {
    pw_h[i] = *(const s16x8*)(Wh + wgoff[i]);
    if (full) pw_l[i] = *(const s16x8*)(Wl + wgoff[i]);
  }

  f32x4 acc[2][4] = {};

  for (int k0 = 0; k0 < KTOT; k0 += BK) {
    __syncthreads();   // previous step's LDS consumers done
    // store prefetched registers to LDS
#pragma unroll
    for (int i = 0; i < 4; i++) {
      *(s16x8*)(ash + ar[i] * 64 + asq[i] * 8) = pa_h[i];
      *(s16x8*)(asl + ar[i] * 64 + asq[i] * 8) = pa_l[i];
    }
#pragma unroll
    for (int i = 0; i < 2; i++) {
      *(s16x8*)(wsh + wr[i] * 64 + wsq[i] * 8) = pw_h[i];
      if (full) *(s16x8*)(wsl + wr[i] * 64 + wsq[i] * 8) = pw_l[i];
    }
    // issue next step's global loads (latency overlaps compute below)
    if (k0 + BK < KTOT) {
      int kn = k0 + BK;
#pragma unroll
      for (int i = 0; i < 4; i++) {
        pa_h[i] = *(const s16x8*)(Ah + agoff[i] + kn);
        pa_l[i] = *(const s16x8*)(Al + agoff[i] + kn);
      }
#pragma unroll
      for (int i = 0; i < 2; i++) {
        pw_h[i] = *(const s16x8*)(Wh + wgoff[i] + kn);
        if (full) pw_l[i] = *(const s16x8*)(Wl + wgoff[i] + kn);
      }
    }
    __syncthreads();   // LDS tile visible
#pragma unroll
    for (int kk = 0; kk < 2; kk++) {
      s16x8 fah[2], fal[2], fbh[4], fbl[4];
#pragma unroll
      for (int rf = 0; rf < 2; rf++) {
        int r = wave * 32 + rf * 16 + lrow;
        int sq = (kk * 4 + quad) ^ (lrow & 7);
        fah[rf] = *(const s16x8*)(ash + r * 64 + sq * 8);
        fal[rf] = *(const s16x8*)(asl + r * 64 + sq * 8);
      }
#pragma unroll
      for (int cf = 0; cf < 4; cf++) {
        int cc = cf * 16 + lrow;
        int sq = (kk * 4 + quad) ^ (lrow & 7);
        fbh[cf] = *(const s16x8*)(wsh + cc * 64 + sq * 8);
        if (full) fbl[cf] = *(const s16x8*)(wsl + cc * 64 + sq * 8);
      }
#pragma unroll
      for (int rf = 0; rf < 2; rf++)
#pragma unroll
        for (int cf = 0; cf < 4; cf++) {
          acc[rf][cf] = __builtin_amdgcn_mfma_f32_16x16x32_bf16(fah[rf], fbh[cf], acc[rf][cf], 0, 0, 0);
          acc[rf][cf] = __builtin_amdgcn_mfma_f32_16x16x32_bf16(fal[rf], fbh[cf], acc[rf][cf], 0, 0, 0);
          if (full)
            acc[rf][cf] = __builtin_amdgcn_mfma_f32_16x16x32_bf16(fah[rf], fbl[cf], acc[rf][cf], 0, 0, 0);
        }
    }
  }
  const float* __restrict__ bias = args.bias[z];
  int obf = args.obf[z];
  if (obf == 0) {
    float* __restrict__ C = args.out[z];
#pragma unroll
    for (int cf = 0; cf < 4; cf++) {
      int col = col0 + cf * 16 + lrow;
      float bv = bias[col];
#pragma unroll
      for (int rf = 0; rf < 2; rf++) {
        int rb = row0 + wave * 32 + rf * 16 + quad * 4;
#pragma unroll
        for (int r = 0; r < 4; r++) {
          int rr = rb + r;
          if (rr < N) C[(size_t)rr * M + col] = acc[rf][cf][r] + bv;
        }
      }
    }
  } else if (obf == 1) {
    unsigned short* __restrict__ C = (unsigned short*)args.out[z];
#pragma unroll
    for (int cf = 0; cf < 4; cf++) {
      int col = col0 + cf * 16 + lrow;
      float bv = bias[col];
#pragma unroll
      for (int rf = 0; rf < 2; rf++) {
        int rb = row0 + wave * 32 + rf * 16 + quad * 4;
#pragma unroll
        for (int r = 0; r < 4; r++) {
          int rr = rb + r;
          if (rr < N) C[(size_t)rr * M + col] = f2bf(acc[rf][cf][r] + bv);
        }
      }
    }
  } else {
    unsigned short* __restrict__ C = (unsigned short*)args.out[z];
    int voff = (obf == 3) ? 4 : 0;
#pragma unroll
    for (int cf = 0; cf < 4; cf++) {
      int col = col0 + cf * 16 + lrow;
      float bv = bias[col];
      int coff = (col >> 2) * 8 + voff + (col & 3);
#pragma unroll
      for (int rf = 0; rf < 2; rf++) {
        int rb = row0 + wave * 32 + rf * 16 + quad * 4;
#pragma unroll
        for (int r = 0; r < 4; r++) {
          int rr = rb + r;
          if (rr < N) C[(size_t)rr * 2 * M + coff] = f2bf(acc[rf][cf][r] + bv);
        }
      }
    }
  }
}

// ---------------- counting sort of edges by dst ----------------

__global__ __launch_bounds__(256) void hist_dst(const int* __restrict__ dst,
                                                int* __restrict__ cnt, int E) {
  int e = blockIdx.x * 256 + threadIdx.x;
  if (e < E) atomicAdd(&cnt[dst[e] + 1], 1);
}

__global__ __launch_bounds__(1024) void scan_hist(const int* __restrict__ cnt,
                                                  int* __restrict__ start,
                                                  int* __restrict__ off, int N) {
  __shared__ int sums[1024];
  const int CH = 20;
  int t = threadIdx.x;
  int base = t * CH;
  int local[CH];
  int tot = 0;
  if (base < N) {
#pragma unroll
    for (int i = 0; i < CH; i++) { local[i] = cnt[base + i]; tot += local[i]; }
  }
  sums[t] = tot;
  __syncthreads();
  for (int d = 1; d < 1024; d <<= 1) {
    int v = (t >= d) ? sums[t - d] : 0;
    __syncthreads();
    sums[t] += v;
    __syncthreads();
  }
  if (base < N) {
    int run = (t == 0) ? 0 : sums[t - 1];
#pragma unroll
    for (int i = 0; i < CH; i++) { start[base + i] = run; off[base + i] = run; run += local[i]; }
    if (base + CH == N) start[N] = run;
  }
}

__global__ __launch_bounds__(256) void scatter_edges(
    const int* __restrict__ src, const int* __restrict__ dst,
    const float* __restrict__ ea, int* __restrict__ off,
    int* __restrict__ src_s, float* __restrict__ ea_s, int* __restrict__ eid_s, int E) {
  int e = blockIdx.x * 256 + threadIdx.x;
  if (e >= E) return;
  int d = dst[e] + 1;
  int pos = atomicAdd(&off[d], 1);
  src_s[pos] = src[e] + 1;
  ea_s[pos] = ea[e];
  eid_s[pos] = e;
}

// ------- fused per-dst attention: kv-interleaved single 16B gather/edge,
// no-max softmax (exact here), algebraic hoists, depth-4 pipeline,
// lane-parallel alpha writeback (invl pulled from head h_of's lane group).
template <int H, int LPH>
__global__ __launch_bounds__(256) void attn_fused(
    const unsigned short* __restrict__ q, const unsigned short* __restrict__ kv,
    const float* __restrict__ We,
    const int* __restrict__ start, const int* __restrict__ src_s,
    const float* __restrict__ ea_s, const int* __restrict__ eid_s,
    float* __restrict__ sc, float* __restrict__ outp,
    float* __restrict__ alpha, int Nn, float scale) {
  const int HC = H * LPH * 4;
  int w = (blockIdx.x * 256 + threadIdx.x) >> 6;
  int lane = threadIdx.x & 63;
  if (w >= Nn) return;
  int b = start[w], e = start[w + 1];
  if (b == e) return;
  bool act = lane < H * LPH;
  int idx = lane * 4;
  int head = lane / LPH;
  float4 q4 = make_float4(0.f, 0.f, 0.f, 0.f), We4 = q4;
  if (act) {
    u16x4 qv = *(const u16x4*)(q + (size_t)w * HC + idx);
    q4.x = bf2f(qv.x); q4.y = bf2f(qv.y); q4.z = bf2f(qv.z); q4.w = bf2f(qv.w);
    We4 = *(const float4*)(We + idx);
  }
  float qwe = q4.x * We4.x + q4.y * We4.y + q4.z * We4.z + q4.w * We4.w;
#pragma unroll
  for (int mm = 1; mm < LPH; mm <<= 1) qwe += __shfl_xor(qwe, mm, 64);

  float l = 0.f, tv = 0.f;
  float4 accv = make_float4(0.f, 0.f, 0.f, 0.f);

  auto step = [&](u16x8 kvv, float eav, int pos) {
    float p = q4.x * bf2f(kvv[0]) + q4.y * bf2f(kvv[1]) +
              q4.z * bf2f(kvv[2]) + q4.w * bf2f(kvv[3]);
#pragma unroll
    for (int mm = 1; mm < LPH; mm <<= 1) p += __shfl_xor(p, mm, 64);
    float es = __expf((p + eav * qwe) * scale);
    if (act && (lane % LPH) == 0) sc[(size_t)pos * H + head] = es;
    l += es;
    tv = fmaf(es, eav, tv);
    accv.x = fmaf(es, bf2f(kvv[4]), accv.x);
    accv.y = fmaf(es, bf2f(kvv[5]), accv.y);
    accv.z = fmaf(es, bf2f(kvv[6]), accv.z);
    accv.w = fmaf(es, bf2f(kvv[7]), accv.w);
  };

  u16x8 z8 = {0, 0, 0, 0, 0, 0, 0, 0};
  u16x8 kvS[4] = {z8, z8, z8, z8};
  float eaS[4] = {0.f, 0.f, 0.f, 0.f};

  auto preload = [&](int pos, int st) {
    int s = src_s[pos]; eaS[st] = ea_s[pos];
    if (act) kvS[st] = *(const u16x8*)(kv + (size_t)s * 2 * HC + lane * 8);
  };

#pragma unroll
  for (int j = 0; j < 4; j++) if (b + j < e) preload(b + j, j);

  for (int pos = b; pos < e; pos += 4) {
#pragma unroll
    for (int j = 0; j < 4; j++) {
      if (pos + j < e) {
        u16x8 kvc = kvS[j];
        float ec = eaS[j];
        if (pos + j + 4 < e) preload(pos + j + 4, j);
        step(kvc, ec, pos + j);
      }
    }
  }

  float invl = 1.0f / (l + 1e-16f);
  if (act) {
    float* orow = outp + (size_t)w * HC + idx;
    float4 o = *(float4*)orow;
    o.x += (accv.x + tv * We4.x) * invl;
    o.y += (accv.y + tv * We4.y) * invl;
    o.z += (accv.z + tv * We4.z) * invl;
    o.w += (accv.w + tv * We4.w) * invl;
    *(float4*)orow = o;
  }
  // lane-parallel alpha writeback: 64/H positions per iteration.
  {
    int len = e - b;
    const int PCH = 64 / H;
    int p_of = lane / H;
    int h_of = lane - p_of * H;
    float myinv = __shfl(invl, h_of * LPH, 64);   // head h_of's denominator
    __threadfence_block();                        // sc stores -> cross-lane reads
    for (int base = 0; base < len; base += PCH) {
      int po = base + p_of;
      if (p_of < PCH && po < len) {
        int pos = b + po;
        float es = sc[(size_t)pos * H + h_of];
        alpha[(size_t)eid_s[pos] * H + h_of] = es * myinv;
      }
    }
  }
}

// ---------------- misc dense kernels ----------------

__global__ __launch_bounds__(256) void ln_relu_split(
    const float* __restrict__ in, const float* __restrict__ g,
    const float* __restrict__ b, unsigned short* __restrict__ hi,
    unsigned short* __restrict__ lo, int N) {
  int w = (blockIdx.x * 256 + threadIdx.x) >> 6;
  int lane = threadIdx.x & 63;
  if (w >= N) return;
  float4 x = *(const float4*)(in + (size_t)w * 256 + lane * 4);
  float s = x.x + x.y + x.z + x.w;
  float s2 = x.x * x.x + x.y * x.y + x.z * x.z + x.w * x.w;
  for (int m = 1; m < 64; m <<= 1) { s += __shfl_xor(s, m, 64); s2 += __shfl_xor(s2, m, 64); }
  float mu = s * (1.0f / 256.0f);
  float var = s2 * (1.0f / 256.0f) - mu * mu;
  float inv = rsqrtf(var + 1e-5f);
  float4 gv = *(const float4*)(g + lane * 4);
  float4 bv = *(const float4*)(b + lane * 4);
  float4 y;
  y.x = fmaxf(fmaf((x.x - mu) * inv, gv.x, bv.x), 0.f);
  y.y = fmaxf(fmaf((x.y - mu) * inv, gv.y, bv.y), 0.f);
  y.z = fmaxf(fmaf((x.z - mu) * inv, gv.z, bv.z), 0.f);
  y.w = fmaxf(fmaf((x.w - mu) * inv, gv.w, bv.w), 0.f);
  u16x4 yh, yl;
  yh.x = f2bf(y.x); yl.x = f2bf(y.x - bf2f(yh.x));
  yh.y = f2bf(y.y); yl.y = f2bf(y.y - bf2f(yh.y));
  yh.z = f2bf(y.z); yl.z = f2bf(y.z - bf2f(yh.z));
  yh.w = f2bf(y.w); yl.w = f2bf(y.w - bf2f(yh.w));
  *(u16x4*)(hi + (size_t)w * 256 + lane * 4) = yh;
  *(u16x4*)(lo + (size_t)w * 256 + lane * 4) = yl;
}

__global__ __launch_bounds__(192) void resid_pool2(
    const float* __restrict__ x, const float* __restrict__ x3,
    const int* __restrict__ batch, float* __restrict__ pooled,
    float* __restrict__ cnt, int N, int R) {
  int col = threadIdx.x;
  int r0 = blockIdx.x * R;
  int r1 = min(r0 + R, N);
  if (r0 >= N) return;
  float acc = 0.f;
  int cur = batch[r0];
  int run = 0;
  for (int r = r0; r < r1; r++) {
    int b = batch[r];
    if (b != cur) {
      atomicAdd(&pooled[cur * 192 + col], acc);
      if (col == 0) atomicAdd(&cnt[cur], (float)run);
      acc = 0.f; run = 0; cur = b;
    }
    size_t i = (size_t)r * 192 + col;
    acc += x[i] + fmaxf(x3[i], 0.f);
    run++;
  }
  atomicAdd(&pooled[cur * 192 + col], acc);
  if (col == 0) atomicAdd(&cnt[cur], (float)run);
}

__global__ __launch_bounds__(64) void head_mlp(
    const float* __restrict__ pooled, const float* __restrict__ cnt,
    const float* __restrict__ fc1w, const float* __restrict__ fc1b,
    const float* __restrict__ fc2w, const float* __restrict__ fc2b,
    float* __restrict__ logits) {
  int b = blockIdx.x;
  int t = threadIdx.x;
  __shared__ float p[192];
  __shared__ float hbuf[32];
  float inv = 1.0f / fmaxf(cnt[b], 1.0f);
  for (int i = t; i < 192; i += 64) p[i] = pooled[b * 192 + i] * inv;
  __syncthreads();
  if (t < 32) {
    float acc = fc1b[t];
    for (int i = 0; i < 192; i++) acc = fmaf(p[i], fc1w[i * 32 + t], acc);
    hbuf[t] = fmaxf(acc, 0.f);
  }
  __syncthreads();
  if (t < 2) {
    float acc = fc2b[t];
    for (int j = 0; j < 32; j++) acc = fmaf(hbuf[j], fc2w[j * 2 + t], acc);
    logits[b * 2 + t] = acc;
  }
}

static inline int divup(int a, int b) { return (a + b - 1) / b; }

extern "C" void kernel_launch(void* const* d_in, const int* in_sizes, int n_in,
                              void* d_out, int out_size, void* d_ws, size_t ws_size,
                              hipStream_t stream) {
  const int N = 20000, E = 320000, B = 64;
  const float* x     = (const float*)d_in[0];
  const int*   ei    = (const int*)d_in[1];
  const float* eattr = (const float*)d_in[2];
  const int*   batch = (const int*)d_in[3];
  const int* srcp = ei;
  const int* dstp = ei + E;

  const float* Wq[3]; const float* bq[3]; const float* Wk[3]; const float* bk[3];
  const float* Wv[3]; const float* bv[3]; const float* We[3]; const float* Ws[3];
  const float* bs[3];
  for (int l = 0; l < 3; l++) {
    int base = 4 + l * 9;
    Wq[l] = (const float*)d_in[base + 0]; bq[l] = (const float*)d_in[base + 1];
    Wk[l] = (const float*)d_in[base + 2]; bk[l] = (const float*)d_in[base + 3];
    Wv[l] = (const float*)d_in[base + 4]; bv[l] = (const float*)d_in[base + 5];
    We[l] = (const float*)d_in[base + 6];
    Ws[l] = (const float*)d_in[base + 7]; bs[l] = (const float*)d_in[base + 8];
  }
  const float* g1  = (const float*)d_in[31]; const float* be1 = (const float*)d_in[32];
  const float* g2  = (const float*)d_in[33]; const float* be2 = (const float*)d_in[34];
  const float* fc1w = (const float*)d_in[35]; const float* fc1b = (const float*)d_in[36];
  const float* fc2w = (const float*)d_in[37]; const float* fc2b = (const float*)d_in[38];

  float* out = (float*)d_out;
  float* logits = out;
  float* a1 = out + 128;
  float* a2 = a1 + (size_t)E * 4;
  float* a3 = a2 + (size_t)E * 4;

  float* ws = (float*)d_ws;
  size_t o = 0;
  float* qb = ws + o; o += (size_t)N * 256;   // bf16 q (oversized ok)
  float* kvb = ws + o; o += (size_t)N * 256;  // bf16 kv interleaved (N*512 u16)
  float* xa = ws + o; o += (size_t)N * 256;
  float* xb = ws + o; o += (size_t)N * 256;
  float* sc = ws + o; o += (size_t)E * 6;
  int*   cntb  = (int*)(ws + o); o += N;
  int*   startb= (int*)(ws + o); o += N + 1;
  int*   offb  = (int*)(ws + o); o += N + 1;
  int*   src_s = (int*)(ws + o); o += E;
  float* ea_s  = ws + o; o += E;
  int*   eid_s = (int*)(ws + o); o += E;
  float* pooled = ws + o; o += (size_t)B * 192;
  float* cnt    = ws + o; o += B;
  unsigned short* Ah = (unsigned short*)(ws + o); o += (size_t)N * 128;
  unsigned short* Al = (unsigned short*)(ws + o); o += (size_t)N * 128;
  unsigned short* Wh12 = (unsigned short*)(ws + o); o += (size_t)12 * 32768;
  unsigned short* Wl12 = (unsigned short*)(ws + o); o += (size_t)12 * 32768;

  unsigned short* qh  = (unsigned short*)qb;
  unsigned short* kvh = (unsigned short*)kvb;

  dim3 blk(256);

  struct LayerCfg { int K, M; float scale; };
  LayerCfg cfg[3] = {
    {192, 256, 0.125f},
    {256, 256, 0.125f},
    {256, 192, 0.1767766952966369f},
  };
  CvtWArgs cwa;
  for (int l = 0; l < 3; l++) {
    cwa.W[l * 4 + 0] = Wq[l]; cwa.W[l * 4 + 1] = Wk[l];
    cwa.W[l * 4 + 2] = Wv[l]; cwa.W[l * 4 + 3] = Ws[l];
    for (int zz = 0; zz < 4; zz++) {
      cwa.K[l * 4 + zz] = cfg[l].K; cwa.M[l * 4 + zz] = cfg[l].M;
    }
  }
  cvt_w_all<<<12 * 65536 / 256, blk, 0, stream>>>(cwa, Wh12, Wl12);

  fill_i32<<<divup(N, 256), blk, 0, stream>>>(cntb, 0, N);
  hist_dst<<<divup(E, 256), blk, 0, stream>>>(dstp, cntb, E);
  scan_hist<<<1, dim3(1024), 0, stream>>>(cntb, startb, offb, N);
  scatter_edges<<<divup(E, 256), blk, 0, stream>>>(srcp, dstp, eattr, offb,
                                                  src_s, ea_s, eid_s, E);

  float*       lay_out[3] = {xa, xb, xa};
  float*       alpha_out[3] = {a1, a2, a3};

  cvt_split<<<divup(N * 192, 256), blk, 0, stream>>>(x, Ah, Al, N * 192);

  for (int l = 0; l < 3; l++) {
    int M = cfg[l].M;
    GemmArgs ga;
    float* outs[4] = {(float*)qh, (float*)kvh, (float*)kvh, lay_out[l]};
    const float* biases[4] = {bq[l], bk[l], bv[l], bs[l]};
    int obfs[4] = {1, 2, 3, 0};
    for (int z = 0; z < 4; z++) {
      ga.Wh[z] = Wh12 + (size_t)(l * 4 + z) * 65536;
      ga.Wl[z] = Wl12 + (size_t)(l * 4 + z) * 65536;
      ga.bias[z] = biases[z];
      ga.out[z] = outs[z];
      ga.obf[z] = obfs[z];
    }
    dim3 gg((M >> 6) * 4, divup(N, 128));
    if (l == 0)      gemm4_lds<192><<<gg, blk, 0, stream>>>(Ah, Al, ga, N, M);
    else             gemm4_lds<256><<<gg, blk, 0, stream>>>(Ah, Al, ga, N, M);

    dim3 gat(divup(N * 64, 256));
    if (l < 2) {
      attn_fused<4, 16><<<gat, blk, 0, stream>>>(qh, kvh, We[l], startb, src_s,
                                                 ea_s, eid_s, sc, lay_out[l],
                                                 alpha_out[l], N, cfg[l].scale);
    } else {
      attn_fused<6, 8><<<gat, blk, 0, stream>>>(qh, kvh, We[l], startb, src_s,
                                                ea_s, eid_s, sc, lay_out[l],
                                                alpha_out[l], N, cfg[l].scale);
    }
    if (l == 0) ln_relu_split<<<divup(N, 4), blk, 0, stream>>>(xa, g1, be1, Ah, Al, N);
    if (l == 1) ln_relu_split<<<divup(N, 4), blk, 0, stream>>>(xb, g2, be2, Ah, Al, N);
  }

  fill_i32<<<divup(B * 192 + B, 256), blk, 0, stream>>>((int*)pooled, 0, B * 192 + B);
  resid_pool2<<<divup(N, 128), dim3(192), 0, stream>>>(x, xa, batch, pooled, cnt, N, 128);
  head_mlp<<<B, dim3(64), 0, stream>>>(pooled, cnt, fc1w, fc1b, fc2w, fc2b, logits);
}

// Round 15
// 626.219 us; speedup vs baseline: 1.1400x; 1.0174x over previous
//
#include <hip/hip_runtime.h>
#include <cstdint>
#include <cstddef>

#define DEVINL __device__ __forceinline__

typedef short s16x8 __attribute__((ext_vector_type(8)));   // 8 bf16 in 4 VGPRs
typedef float f32x4 __attribute__((ext_vector_type(4)));
typedef unsigned short u16x4 __attribute__((ext_vector_type(4)));
typedef unsigned short u16x8 __attribute__((ext_vector_type(8)));

DEVINL unsigned short f2bf(float f) {
  unsigned u = __float_as_uint(f);
  unsigned r = (u + 0x7FFFu + ((u >> 16) & 1u)) >> 16;
  return (unsigned short)r;
}
DEVINL float bf2f(unsigned short b) { return __uint_as_float(((unsigned)b) << 16); }

__global__ __launch_bounds__(256) void fill_i32(int* __restrict__ p, int val, int n) {
  int i = blockIdx.x * 256 + threadIdx.x;
  if (i < n) p[i] = val;
}

// ---------------- bf16 hi/lo split conversions ----------------

__global__ __launch_bounds__(256) void cvt_split(const float* __restrict__ in,
                                                 unsigned short* __restrict__ hi,
                                                 unsigned short* __restrict__ lo, int n) {
  int i = blockIdx.x * 256 + threadIdx.x;
  if (i >= n) return;
  float f = in[i];
  unsigned short h = f2bf(f);
  float r = f - bf2f(h);
  hi[i] = h;
  lo[i] = f2bf(r);
}

// all 12 weight matrices in one launch: W[K,M] fp32 -> Wt hi/lo [M,K] bf16
struct CvtWArgs {
  const float* W[12];
  int K[12];
  int M[12];
};
__global__ __launch_bounds__(256) void cvt_w_all(CvtWArgs a,
                                                 unsigned short* __restrict__ Wh,
                                                 unsigned short* __restrict__ Wl) {
  int tid = blockIdx.x * 256 + threadIdx.x;
  int mat = tid >> 16;
  int off = tid & 65535;
  if (mat >= 12) return;
  int K = a.K[mat], M = a.M[mat];
  if (off >= K * M) return;
  int k = off / M, m = off - k * M;
  float f = a.W[mat][off];
  unsigned short h = f2bf(f);
  float r = f - bf2f(h);
  size_t dst = (size_t)mat * 65536 + (size_t)m * K + k;
  Wh[dst] = h;
  Wl[dst] = f2bf(r);
}

// ---------------- LDS-tiled fused 4-matrix MFMA GEMM -------
// XOR-swizzled unpadded LDS, 48 KB -> 3 blocks/CU; register-prefetch double
// buffer (R13).  R14: bf16 outputs (obf 1/2/3) stage the C-tile through LDS
// (reusing ash after the K-loop) and store dense row-major chunks — R12/13
// WRITE_SIZE was 77 MB vs ~50 ideal because per-lane column-walk stores wrote
// 2 B elements at stride-16B (kv) / 32B-partial lines (q).
// obf: 0 = fp32 row, 1 = bf16 row (q), 2/3 = bf16 kv-interleaved k/v slot.
struct GemmArgs {
  const unsigned short* Wh[4];
  const unsigned short* Wl[4];
  const float* bias[4];
  float* out[4];
  int obf[4];
};

template <int KTOT>   // 192 or 256
__global__ __launch_bounds__(256, 3) void gemm4_lds(
    const unsigned short* __restrict__ Ah, const unsigned short* __restrict__ Al,
    GemmArgs args, int N, int M) {
  const int BK = 64;
  __shared__ unsigned short ash[128 * 64];
  __shared__ unsigned short asl[128 * 64];
  __shared__ unsigned short wsh[64 * 64];
  __shared__ unsigned short wsl[64 * 64];
  int tid = threadIdx.x;
  int wave = tid >> 6, lane = tid & 63;
  int lrow = lane & 15, quad = lane >> 4;
  int mt = M >> 6;
  int z = blockIdx.x / mt;
  int colTile = blockIdx.x - z * mt;
  int row0 = blockIdx.y * 128;
  int col0 = colTile * 64;
  const unsigned short* __restrict__ Wh = args.Wh[z];
  const unsigned short* __restrict__ Wl = args.Wl[z];
  const bool full = (args.obf[z] == 0);

  // per-thread staging geometry (loop-invariant)
  int ar[4], asq[4];
  size_t agoff[4];
#pragma unroll
  for (int i = 0; i < 4; i++) {
    int c = tid + i * 256;
    ar[i] = c >> 3;
    int kq = c & 7;
    asq[i] = kq ^ (ar[i] & 7);
    int gr = row0 + ar[i]; if (gr >= N) gr = N - 1;
    agoff[i] = (size_t)gr * KTOT + kq * 8;
  }
  int wr[2], wsq[2];
  size_t wgoff[2];
#pragma unroll
  for (int i = 0; i < 2; i++) {
    int c = tid + i * 256;
    wr[i] = c >> 3;
    int kq = c & 7;
    wsq[i] = kq ^ (wr[i] & 7);
    wgoff[i] = (size_t)(col0 + wr[i]) * KTOT + kq * 8;
  }

  // prologue: prefetch step 0
  s16x8 pa_h[4], pa_l[4], pw_h[2], pw_l[2];
#pragma unroll
  for (int i = 0; i < 4; i++) {
    pa_h[i] = *(const s16x8*)(Ah + agoff[i]);
    pa_l[i] = *(const s16x8*)(Al + agoff[i]);
  }
#pragma unroll
  for (int i = 0; i < 2; i++) {
    pw_h[i] = *(const s16x8*)(Wh + wgoff[i]);
    if (full) pw_l[i] = *(const s16x8*)(Wl + wgoff[i]);
  }

  f32x4 acc[2][4] = {};

  for (int k0 = 0; k0 < KTOT; k0 += BK) {
    __syncthreads();   // previous step's LDS consumers done
#pragma unroll
    for (int i = 0; i < 4; i++) {
      *(s16x8*)(ash + ar[i] * 64 + asq[i] * 8) = pa_h[i];
      *(s16x8*)(asl + ar[i] * 64 + asq[i] * 8) = pa_l[i];
    }
#pragma unroll
    for (int i = 0; i < 2; i++) {
      *(s16x8*)(wsh + wr[i] * 64 + wsq[i] * 8) = pw_h[i];
      if (full) *(s16x8*)(wsl + wr[i] * 64 + wsq[i] * 8) = pw_l[i];
    }
    if (k0 + BK < KTOT) {
      int kn = k0 + BK;
#pragma unroll
      for (int i = 0; i < 4; i++) {
        pa_h[i] = *(const s16x8*)(Ah + agoff[i] + kn);
        pa_l[i] = *(const s16x8*)(Al + agoff[i] + kn);
      }
#pragma unroll
      for (int i = 0; i < 2; i++) {
        pw_h[i] = *(const s16x8*)(Wh + wgoff[i] + kn);
        if (full) pw_l[i] = *(const s16x8*)(Wl + wgoff[i] + kn);
      }
    }
    __syncthreads();   // LDS tile visible
#pragma unroll
    for (int kk = 0; kk < 2; kk++) {
      s16x8 fah[2], fal[2], fbh[4], fbl[4];
#pragma unroll
      for (int rf = 0; rf < 2; rf++) {
        int r = wave * 32 + rf * 16 + lrow;
        int sq = (kk * 4 + quad) ^ (lrow & 7);
        fah[rf] = *(const s16x8*)(ash + r * 64 + sq * 8);
        fal[rf] = *(const s16x8*)(asl + r * 64 + sq * 8);
      }
#pragma unroll
      for (int cf = 0; cf < 4; cf++) {
        int cc = cf * 16 + lrow;
        int sq = (kk * 4 + quad) ^ (lrow & 7);
        fbh[cf] = *(const s16x8*)(wsh + cc * 64 + sq * 8);
        if (full) fbl[cf] = *(const s16x8*)(wsl + cc * 64 + sq * 8);
      }
#pragma unroll
      for (int rf = 0; rf < 2; rf++)
#pragma unroll
        for (int cf = 0; cf < 4; cf++) {
          acc[rf][cf] = __builtin_amdgcn_mfma_f32_16x16x32_bf16(fah[rf], fbh[cf], acc[rf][cf], 0, 0, 0);
          acc[rf][cf] = __builtin_amdgcn_mfma_f32_16x16x32_bf16(fal[rf], fbh[cf], acc[rf][cf], 0, 0, 0);
          if (full)
            acc[rf][cf] = __builtin_amdgcn_mfma_f32_16x16x32_bf16(fah[rf], fbl[cf], acc[rf][cf], 0, 0, 0);
        }
    }
  }
  const float* __restrict__ bias = args.bias[z];
  int obf = args.obf[z];
  if (obf == 0) {
    // fp32 direct stores: each instr covers 4 full 64B lines — already fine
    float* __restrict__ C = args.out[z];
#pragma unroll
    for (int cf = 0; cf < 4; cf++) {
      int col = col0 + cf * 16 + lrow;
      float bv = bias[col];
#pragma unroll
      for (int rf = 0; rf < 2; rf++) {
        int rb = row0 + wave * 32 + rf * 16 + quad * 4;
#pragma unroll
        for (int r = 0; r < 4; r++) {
          int rr = rb + r;
          if (rr < N) C[(size_t)rr * M + col] = acc[rf][cf][r] + bv;
        }
      }
    }
  } else {
    // bf16 modes: stage u16 tile in ash (free after K-loop), store dense
    __syncthreads();
#pragma unroll
    for (int cf = 0; cf < 4; cf++) {
      int col = cf * 16 + lrow;
      float bv = bias[col0 + col];
#pragma unroll
      for (int rf = 0; rf < 2; rf++) {
        int rl = wave * 32 + rf * 16 + quad * 4;
#pragma unroll
        for (int r = 0; r < 4; r++)
          ash[(rl + r) * 64 + col] = f2bf(acc[rf][cf][r] + bv);
      }
    }
    __syncthreads();
    unsigned short* __restrict__ C = (unsigned short*)args.out[z];
    if (obf == 1) {
      // q: row-major M cols, 16B chunks.  1024 chunks / 256 threads.
#pragma unroll
      for (int i = 0; i < 4; i++) {
        int c = tid + i * 256;
        int row = c >> 3, g8 = c & 7;
        int rr = row0 + row;
        if (rr < N)
          *(u16x8*)(C + (size_t)rr * M + col0 + g8 * 8) =
              *(const u16x8*)(ash + row * 64 + g8 * 8);
      }
    } else {
      // kv half: groups of 4 cols -> 8B store at (col/4)*8 + voff
      int voff = (obf == 3) ? 4 : 0;
      int gbase = col0 >> 2;
#pragma unroll
      for (int i = 0; i < 8; i++) {
        int c = tid + i * 256;
        int row = c >> 4, g4 = c & 15;
        int rr = row0 + row;
        if (rr < N)
          *(u16x4*)(C + (size_t)rr * 2 * M + (size_t)(gbase + g4) * 8 + voff) =
              *(const u16x4*)(ash + row * 64 + g4 * 4);
      }
    }
  }
}

// ---------------- counting sort of edges by dst ----------------

__global__ __launch_bounds__(256) void hist_dst(const int* __restrict__ dst,
                                                int* __restrict__ cnt, int E) {
  int e = blockIdx.x * 256 + threadIdx.x;
  if (e < E) atomicAdd(&cnt[dst[e] + 1], 1);
}

__global__ __launch_bounds__(1024) void scan_hist(const int* __restrict__ cnt,
                                                  int* __restrict__ start,
                                                  int* __restrict__ off, int N) {
  __shared__ int sums[1024];
  const int CH = 20;
  int t = threadIdx.x;
  int base = t * CH;
  int local[CH];
  int tot = 0;
  if (base < N) {
#pragma unroll
    for (int i = 0; i < CH; i++) { local[i] = cnt[base + i]; tot += local[i]; }
  }
  sums[t] = tot;
  __syncthreads();
  for (int d = 1; d < 1024; d <<= 1) {
    int v = (t >= d) ? sums[t - d] : 0;
    __syncthreads();
    sums[t] += v;
    __syncthreads();
  }
  if (base < N) {
    int run = (t == 0) ? 0 : sums[t - 1];
#pragma unroll
    for (int i = 0; i < CH; i++) { start[base + i] = run; off[base + i] = run; run += local[i]; }
    if (base + CH == N) start[N] = run;
  }
}

__global__ __launch_bounds__(256) void scatter_edges(
    const int* __restrict__ src, const int* __restrict__ dst,
    const float* __restrict__ ea, int* __restrict__ off,
    int* __restrict__ src_s, float* __restrict__ ea_s, int* __restrict__ eid_s, int E) {
  int e = blockIdx.x * 256 + threadIdx.x;
  if (e >= E) return;
  int d = dst[e] + 1;
  int pos = atomicAdd(&off[d], 1);
  src_s[pos] = src[e] + 1;
  ea_s[pos] = ea[e];
  eid_s[pos] = e;
}

// ------- fused per-dst attention: kv-interleaved single 16B gather/edge,
// no-max softmax (exact here), algebraic hoists, depth-4 pipeline,
// lane-parallel alpha writeback (invl pulled from head h_of's lane group).
template <int H, int LPH>
__global__ __launch_bounds__(256) void attn_fused(
    const unsigned short* __restrict__ q, const unsigned short* __restrict__ kv,
    const float* __restrict__ We,
    const int* __restrict__ start, const int* __restrict__ src_s,
    const float* __restrict__ ea_s, const int* __restrict__ eid_s,
    float* __restrict__ sc, float* __restrict__ outp,
    float* __restrict__ alpha, int Nn, float scale) {
  const int HC = H * LPH * 4;
  int w = (blockIdx.x * 256 + threadIdx.x) >> 6;
  int lane = threadIdx.x & 63;
  if (w >= Nn) return;
  int b = start[w], e = start[w + 1];
  if (b == e) return;
  bool act = lane < H * LPH;
  int idx = lane * 4;
  int head = lane / LPH;
  float4 q4 = make_float4(0.f, 0.f, 0.f, 0.f), We4 = q4;
  if (act) {
    u16x4 qv = *(const u16x4*)(q + (size_t)w * HC + idx);
    q4.x = bf2f(qv.x); q4.y = bf2f(qv.y); q4.z = bf2f(qv.z); q4.w = bf2f(qv.w);
    We4 = *(const float4*)(We + idx);
  }
  float qwe = q4.x * We4.x + q4.y * We4.y + q4.z * We4.z + q4.w * We4.w;
#pragma unroll
  for (int mm = 1; mm < LPH; mm <<= 1) qwe += __shfl_xor(qwe, mm, 64);

  float l = 0.f, tv = 0.f;
  float4 accv = make_float4(0.f, 0.f, 0.f, 0.f);

  auto step = [&](u16x8 kvv, float eav, int pos) {
    float p = q4.x * bf2f(kvv[0]) + q4.y * bf2f(kvv[1]) +
              q4.z * bf2f(kvv[2]) + q4.w * bf2f(kvv[3]);
#pragma unroll
    for (int mm = 1; mm < LPH; mm <<= 1) p += __shfl_xor(p, mm, 64);
    float es = __expf((p + eav * qwe) * scale);
    if (act && (lane % LPH) == 0) sc[(size_t)pos * H + head] = es;
    l += es;
    tv = fmaf(es, eav, tv);
    accv.x = fmaf(es, bf2f(kvv[4]), accv.x);
    accv.y = fmaf(es, bf2f(kvv[5]), accv.y);
    accv.z = fmaf(es, bf2f(kvv[6]), accv.z);
    accv.w = fmaf(es, bf2f(kvv[7]), accv.w);
  };

  u16x8 z8 = {0, 0, 0, 0, 0, 0, 0, 0};
  u16x8 kvS[4] = {z8, z8, z8, z8};
  float eaS[4] = {0.f, 0.f, 0.f, 0.f};

  auto preload = [&](int pos, int st) {
    int s = src_s[pos]; eaS[st] = ea_s[pos];
    if (act) kvS[st] = *(const u16x8*)(kv + (size_t)s * 2 * HC + lane * 8);
  };

#pragma unroll
  for (int j = 0; j < 4; j++) if (b + j < e) preload(b + j, j);

  for (int pos = b; pos < e; pos += 4) {
#pragma unroll
    for (int j = 0; j < 4; j++) {
      if (pos + j < e) {
        u16x8 kvc = kvS[j];
        float ec = eaS[j];
        if (pos + j + 4 < e) preload(pos + j + 4, j);
        step(kvc, ec, pos + j);
      }
    }
  }

  float invl = 1.0f / (l + 1e-16f);
  if (act) {
    float* orow = outp + (size_t)w * HC + idx;
    float4 o = *(float4*)orow;
    o.x += (accv.x + tv * We4.x) * invl;
    o.y += (accv.y + tv * We4.y) * invl;
    o.z += (accv.z + tv * We4.z) * invl;
    o.w += (accv.w + tv * We4.w) * invl;
    *(float4*)orow = o;
  }
  {
    int len = e - b;
    const int PCH = 64 / H;
    int p_of = lane / H;
    int h_of = lane - p_of * H;
    float myinv = __shfl(invl, h_of * LPH, 64);   // head h_of's denominator
    __threadfence_block();
    for (int base = 0; base < len; base += PCH) {
      int po = base + p_of;
      if (p_of < PCH && po < len) {
        int pos = b + po;
        float es = sc[(size_t)pos * H + h_of];
        alpha[(size_t)eid_s[pos] * H + h_of] = es * myinv;
      }
    }
  }
}

// ---------------- misc dense kernels ----------------

__global__ __launch_bounds__(256) void ln_relu_split(
    const float* __restrict__ in, const float* __restrict__ g,
    const float* __restrict__ b, unsigned short* __restrict__ hi,
    unsigned short* __restrict__ lo, int N) {
  int w = (blockIdx.x * 256 + threadIdx.x) >> 6;
  int lane = threadIdx.x & 63;
  if (w >= N) return;
  float4 x = *(const float4*)(in + (size_t)w * 256 + lane * 4);
  float s = x.x + x.y + x.z + x.w;
  float s2 = x.x * x.x + x.y * x.y + x.z * x.z + x.w * x.w;
  for (int m = 1; m < 64; m <<= 1) { s += __shfl_xor(s, m, 64); s2 += __shfl_xor(s2, m, 64); }
  float mu = s * (1.0f / 256.0f);
  float var = s2 * (1.0f / 256.0f) - mu * mu;
  float inv = rsqrtf(var + 1e-5f);
  float4 gv = *(const float4*)(g + lane * 4);
  float4 bv = *(const float4*)(b + lane * 4);
  float4 y;
  y.x = fmaxf(fmaf((x.x - mu) * inv, gv.x, bv.x), 0.f);
  y.y = fmaxf(fmaf((x.y - mu) * inv, gv.y, bv.y), 0.f);
  y.z = fmaxf(fmaf((x.z - mu) * inv, gv.z, bv.z), 0.f);
  y.w = fmaxf(fmaf((x.w - mu) * inv, gv.w, bv.w), 0.f);
  u16x4 yh, yl;
  yh.x = f2bf(y.x); yl.x = f2bf(y.x - bf2f(yh.x));
  yh.y = f2bf(y.y); yl.y = f2bf(y.y - bf2f(yh.y));
  yh.z = f2bf(y.z); yl.z = f2bf(y.z - bf2f(yh.z));
  yh.w = f2bf(y.w); yl.w = f2bf(y.w - bf2f(yh.w));
  *(u16x4*)(hi + (size_t)w * 256 + lane * 4) = yh;
  *(u16x4*)(lo + (size_t)w * 256 + lane * 4) = yl;
}

__global__ __launch_bounds__(192) void resid_pool2(
    const float* __restrict__ x, const float* __restrict__ x3,
    const int* __restrict__ batch, float* __restrict__ pooled,
    float* __restrict__ cnt, int N, int R) {
  int col = threadIdx.x;
  int r0 = blockIdx.x * R;
  int r1 = min(r0 + R, N);
  if (r0 >= N) return;
  float acc = 0.f;
  int cur = batch[r0];
  int run = 0;
  for (int r = r0; r < r1; r++) {
    int b = batch[r];
    if (b != cur) {
      atomicAdd(&pooled[cur * 192 + col], acc);
      if (col == 0) atomicAdd(&cnt[cur], (float)run);
      acc = 0.f; run = 0; cur = b;
    }
    size_t i = (size_t)r * 192 + col;
    acc += x[i] + fmaxf(x3[i], 0.f);
    run++;
  }
  atomicAdd(&pooled[cur * 192 + col], acc);
  if (col == 0) atomicAdd(&cnt[cur], (float)run);
}

__global__ __launch_bounds__(64) void head_mlp(
    const float* __restrict__ pooled, const float* __restrict__ cnt,
    const float* __restrict__ fc1w, const float* __restrict__ fc1b,
    const float* __restrict__ fc2w, const float* __restrict__ fc2b,
    float* __restrict__ logits) {
  int b = blockIdx.x;
  int t = threadIdx.x;
  __shared__ float p[192];
  __shared__ float hbuf[32];
  float inv = 1.0f / fmaxf(cnt[b], 1.0f);
  for (int i = t; i < 192; i += 64) p[i] = pooled[b * 192 + i] * inv;
  __syncthreads();
  if (t < 32) {
    float acc = fc1b[t];
    for (int i = 0; i < 192; i++) acc = fmaf(p[i], fc1w[i * 32 + t], acc);
    hbuf[t] = fmaxf(acc, 0.f);
  }
  __syncthreads();
  if (t < 2) {
    float acc = fc2b[t];
    for (int j = 0; j < 32; j++) acc = fmaf(hbuf[j], fc2w[j * 2 + t], acc);
    logits[b * 2 + t] = acc;
  }
}

static inline int divup(int a, int b) { return (a + b - 1) / b; }

extern "C" void kernel_launch(void* const* d_in, const int* in_sizes, int n_in,
                              void* d_out, int out_size, void* d_ws, size_t ws_size,
                              hipStream_t stream) {
  const int N = 20000, E = 320000, B = 64;
  const float* x     = (const float*)d_in[0];
  const int*   ei    = (const int*)d_in[1];
  const float* eattr = (const float*)d_in[2];
  const int*   batch = (const int*)d_in[3];
  const int* srcp = ei;
  const int* dstp = ei + E;

  const float* Wq[3]; const float* bq[3]; const float* Wk[3]; const float* bk[3];
  const float* Wv[3]; const float* bv[3]; const float* We[3]; const float* Ws[3];
  const float* bs[3];
  for (int l = 0; l < 3; l++) {
    int base = 4 + l * 9;
    Wq[l] = (const float*)d_in[base + 0]; bq[l] = (const float*)d_in[base + 1];
    Wk[l] = (const float*)d_in[base + 2]; bk[l] = (const float*)d_in[base + 3];
    Wv[l] = (const float*)d_in[base + 4]; bv[l] = (const float*)d_in[base + 5];
    We[l] = (const float*)d_in[base + 6];
    Ws[l] = (const float*)d_in[base + 7]; bs[l] = (const float*)d_in[base + 8];
  }
  const float* g1  = (const float*)d_in[31]; const float* be1 = (const float*)d_in[32];
  const float* g2  = (const float*)d_in[33]; const float* be2 = (const float*)d_in[34];
  const float* fc1w = (const float*)d_in[35]; const float* fc1b = (const float*)d_in[36];
  const float* fc2w = (const float*)d_in[37]; const float* fc2b = (const float*)d_in[38];

  float* out = (float*)d_out;
  float* logits = out;
  float* a1 = out + 128;
  float* a2 = a1 + (size_t)E * 4;
  float* a3 = a2 + (size_t)E * 4;

  float* ws = (float*)d_ws;
  size_t o = 0;
  float* qb = ws + o; o += (size_t)N * 256;   // bf16 q (oversized ok)
  float* kvb = ws + o; o += (size_t)N * 256;  // bf16 kv interleaved (N*512 u16)
  float* xa = ws + o; o += (size_t)N * 256;
  float* xb = ws + o; o += (size_t)N * 256;
  float* sc = ws + o; o += (size_t)E * 6;
  int*   cntb  = (int*)(ws + o); o += N;
  int*   startb= (int*)(ws + o); o += N + 1;
  int*   offb  = (int*)(ws + o); o += N + 1;
  int*   src_s = (int*)(ws + o); o += E;
  float* ea_s  = ws + o; o += E;
  int*   eid_s = (int*)(ws + o); o += E;
  float* pooled = ws + o; o += (size_t)B * 192;
  float* cnt    = ws + o; o += B;
  unsigned short* Ah = (unsigned short*)(ws + o); o += (size_t)N * 128;
  unsigned short* Al = (unsigned short*)(ws + o); o += (size_t)N * 128;
  unsigned short* Wh12 = (unsigned short*)(ws + o); o += (size_t)12 * 32768;
  unsigned short* Wl12 = (unsigned short*)(ws + o); o += (size_t)12 * 32768;

  unsigned short* qh  = (unsigned short*)qb;
  unsigned short* kvh = (unsigned short*)kvb;

  dim3 blk(256);

  struct LayerCfg { int K, M; float scale; };
  LayerCfg cfg[3] = {
    {192, 256, 0.125f},
    {256, 256, 0.125f},
    {256, 192, 0.1767766952966369f},
  };
  CvtWArgs cwa;
  for (int l = 0; l < 3; l++) {
    cwa.W[l * 4 + 0] = Wq[l]; cwa.W[l * 4 + 1] = Wk[l];
    cwa.W[l * 4 + 2] = Wv[l]; cwa.W[l * 4 + 3] = Ws[l];
    for (int zz = 0; zz < 4; zz++) {
      cwa.K[l * 4 + zz] = cfg[l].K; cwa.M[l * 4 + zz] = cfg[l].M;
    }
  }
  cvt_w_all<<<12 * 65536 / 256, blk, 0, stream>>>(cwa, Wh12, Wl12);

  fill_i32<<<divup(N, 256), blk, 0, stream>>>(cntb, 0, N);
  hist_dst<<<divup(E, 256), blk, 0, stream>>>(dstp, cntb, E);
  scan_hist<<<1, dim3(1024), 0, stream>>>(cntb, startb, offb, N);
  scatter_edges<<<divup(E, 256), blk, 0, stream>>>(srcp, dstp, eattr, offb,
                                                  src_s, ea_s, eid_s, E);

  float*       lay_out[3] = {xa, xb, xa};
  float*       alpha_out[3] = {a1, a2, a3};

  cvt_split<<<divup(N * 192, 256), blk, 0, stream>>>(x, Ah, Al, N * 192);

  for (int l = 0; l < 3; l++) {
    int M = cfg[l].M;
    GemmArgs ga;
    float* outs[4] = {(float*)qh, (float*)kvh, (float*)kvh, lay_out[l]};
    const float* biases[4] = {bq[l], bk[l], bv[l], bs[l]};
    int obfs[4] = {1, 2, 3, 0};
    for (int z = 0; z < 4; z++) {
      ga.Wh[z] = Wh12 + (size_t)(l * 4 + z) * 65536;
      ga.Wl[z] = Wl12 + (size_t)(l * 4 + z) * 65536;
      ga.bias[z] = biases[z];
      ga.out[z] = outs[z];
      ga.obf[z] = obfs[z];
    }
    dim3 gg((M >> 6) * 4, divup(N, 128));
    if (l == 0)      gemm4_lds<192><<<gg, blk, 0, stream>>>(Ah, Al, ga, N, M);
    else             gemm4_lds<256><<<gg, blk, 0, stream>>>(Ah, Al, ga, N, M);

    dim3 gat(divup(N * 64, 256));
    if (l < 2) {
      attn_fused<4, 16><<<gat, blk, 0, stream>>>(qh, kvh, We[l], startb, src_s,
                                                 ea_s, eid_s, sc, lay_out[l],
                                                 alpha_out[l], N, cfg[l].scale);
    } else {
      attn_fused<6, 8><<<gat, blk, 0, stream>>>(qh, kvh, We[l], startb, src_s,
                                                ea_s, eid_s, sc, lay_out[l],
                                                alpha_out[l], N, cfg[l].scale);
    }
    if (l == 0) ln_relu_split<<<divup(N, 4), blk, 0, stream>>>(xa, g1, be1, Ah, Al, N);
    if (l == 1) ln_relu_split<<<divup(N, 4), blk, 0, stream>>>(xb, g2, be2, Ah, Al, N);
  }

  fill_i32<<<divup(B * 192 + B, 256), blk, 0, stream>>>((int*)pooled, 0, B * 192 + B);
  resid_pool2<<<divup(N, 32), dim3(192), 0, stream>>>(x, xa, batch, pooled, cnt, N, 32);
  head_mlp<<<B, dim3(64), 0, stream>>>(pooled, cnt, fc1w, fc1b, fc2w, fc2b, logits);
}